// Round 5
// baseline (386.167 us; speedup 1.0000x reference)
//
#include <hip/hip_runtime.h>
#include <math.h>

#define B_  2
#define H_  64
#define W_  64
#define HW  4096
#define DM  96
#define DI  192
#define NS  4
#define RK  6
#define KD  2
#define LL  8192   // 2*HW

__device__ __forceinline__ float sigmoidf_(float x){ return 1.f/(1.f+__expf(-x)); }

// ---------------- K0: zero the sr accumulator ----------------
__global__ void k_zero(float* __restrict__ p, int n){
  int i = blockIdx.x*256 + threadIdx.x;
  if (i < n) p[i] = 0.f;
}

// ---------------- K1: input projections -> channel-major [B,DI,HW] + fused channel sums ----------------
__global__ __launch_bounds__(256) void k_inproj(
    const float* __restrict__ xrgb, const float* __restrict__ xe,
    const float* __restrict__ wr,   const float* __restrict__ we,
    float* __restrict__ xrt, float* __restrict__ xet, float* __restrict__ sr)
{
  __shared__ float lsW[DI*100];
  __shared__ float lsum[DI];
  const int mod = blockIdx.z, b = blockIdx.y;
  const int hw0 = blockIdx.x * 64;
  const float* x  = mod ? xe  : xrgb;
  const float* Wp = mod ? we  : wr;
  float* out      = mod ? xet : xrt;
  const int tid = threadIdx.x;
  for (int t = tid; t < DI*DM; t += 256){
    int di = t / DM, kk = t - di*DM;
    lsW[di*100 + kk] = Wp[t];
  }
  if (tid < DI) lsum[tid] = 0.f;
  const int cg = tid & 31, slot = tid >> 5;   // 8 slots
  const int r0 = slot * 8;
  const float* xb = x + ((size_t)(b*HW) + hw0 + r0)*DM;
  float acc[8][6];
  #pragma unroll
  for (int i=0;i<8;i++)
    #pragma unroll
    for (int q=0;q<6;q++) acc[i][q]=0.f;
  __syncthreads();
  for (int kk4=0; kk4<DM/4; kk4++){
    float4 xv[8];
    #pragma unroll
    for (int i=0;i<8;i++) xv[i] = *(const float4*)(xb + (size_t)i*DM + kk4*4);
    #pragma unroll
    for (int q=0;q<6;q++){
      const float4 wv = *(const float4*)(&lsW[(cg+32*q)*100 + kk4*4]);
      #pragma unroll
      for (int i=0;i<8;i++){
        acc[i][q] = fmaf(xv[i].x, wv.x, acc[i][q]);
        acc[i][q] = fmaf(xv[i].y, wv.y, acc[i][q]);
        acc[i][q] = fmaf(xv[i].z, wv.z, acc[i][q]);
        acc[i][q] = fmaf(xv[i].w, wv.w, acc[i][q]);
      }
    }
  }
  #pragma unroll
  for (int q=0;q<6;q++){
    int di = cg + 32*q;
    float* ob = out + ((size_t)(b*DI + di))*HW + hw0 + r0;
    float ps = 0.f;
    #pragma unroll
    for (int i=0;i<8;i++){ ob[i] = acc[i][q]; ps += acc[i][q]; }
    atomicAdd(&lsum[di], ps);
  }
  __syncthreads();
  if (tid < DI) atomicAdd(&sr[((size_t)mod*B_ + b)*DI + tid], lsum[tid]);
}

// ---------------- K2: depthwise 3x3 conv + SiLU -> seq[B,DI,2HW] ----------------
__global__ __launch_bounds__(256) void k_conv(
    const float* __restrict__ xrt, const float* __restrict__ xet,
    const float* __restrict__ cwr, const float* __restrict__ cbr,
    const float* __restrict__ cwe, const float* __restrict__ cbe,
    float* __restrict__ seq)
{
  const int z = blockIdx.z; const int b = z >> 1, mod = z & 1;
  const int d = blockIdx.y;
  const float* in = (mod? xet:xrt) + ((size_t)b*DI + d)*HW;
  const float* wp = (mod? cwe:cwr) + d*9;
  const float  bias = (mod? cbe:cbr)[d];
  const int hw = blockIdx.x*256 + threadIdx.x;
  const int y = hw >> 6, x = hw & 63;
  float w[9];
  #pragma unroll
  for (int i=0;i<9;i++) w[i]=wp[i];
  float acc = bias;
  #pragma unroll
  for (int dy=-1;dy<=1;dy++){
    int yy = y+dy;
    if (yy<0||yy>=H_) continue;
    #pragma unroll
    for (int dx=-1;dx<=1;dx++){
      int xx = x+dx;
      if (xx<0||xx>=W_) continue;
      acc += in[yy*W_+xx]*w[(dy+1)*3 + dx+1];
    }
  }
  float v = acc * sigmoidf_(acc);
  seq[((size_t)b*DI + d)*LL + mod*HW + hw] = v;
}

// ---------------- K3: squeeze-excitation MLP (sr holds channel SUMS; scale by 1/HW) ----------------
__global__ void k_se(const float* __restrict__ sr,
                     const float* __restrict__ f11, const float* __restrict__ f12,
                     const float* __restrict__ f21, const float* __restrict__ f22,
                     float* __restrict__ ex)
{
  const int b = blockIdx.x, mod = blockIdx.y;
  const float* f1 = mod? f21:f11;
  const float* f2 = mod? f22:f12;
  __shared__ float s[DI];
  __shared__ float hid[12];
  const int t = threadIdx.x;
  s[t] = sr[((size_t)mod*B_ + b)*DI + t] * (1.f/HW);
  __syncthreads();
  if (t < 12){
    float a=0.f;
    for (int dd=0; dd<DI; dd++) a += f1[t*DI+dd]*s[dd];
    hid[t] = a * sigmoidf_(a);
  }
  __syncthreads();
  float a=0.f;
  #pragma unroll
  for (int h=0; h<12; h++) a += f2[t*12+h]*hid[h];
  ex[((size_t)mod*B_ + b)*DI + t] = sigmoidf_(a);
}

// ---------------- K4: x_proj of seq -> draw[j][6], Bp[j][4], Cp[j][4] ----------------
__global__ __launch_bounds__(256) void k_proj(
    const float* __restrict__ seq, const float* __restrict__ xpw,
    float* __restrict__ draw, float* __restrict__ Bp, float* __restrict__ Cp)
{
  __shared__ float lw[14*DI];
  const int b = blockIdx.z, k = blockIdx.y;
  const int j = blockIdx.x*256 + threadIdx.x;
  for (int t = threadIdx.x; t < 14*DI; t += 256) lw[t] = xpw[(size_t)k*14*DI + t];
  __syncthreads();
  float acc[14];
  #pragma unroll
  for (int c=0;c<14;c++) acc[c]=0.f;
  const float* sp = seq + (size_t)b*DI*LL + j;
  for (int dd=0; dd<DI; dd++){
    float s = sp[(size_t)dd*LL];
    #pragma unroll
    for (int cc=0; cc<14; cc++) acc[cc] = fmaf(lw[cc*DI+dd], s, acc[cc]);
  }
  const int bk = b*KD + k;
  float2* dout = (float2*)(draw + ((size_t)bk*LL + j)*6);
  dout[0] = make_float2(acc[0],acc[1]);
  dout[1] = make_float2(acc[2],acc[3]);
  dout[2] = make_float2(acc[4],acc[5]);
  *(float4*)(Bp + ((size_t)bk*LL + j)*4) = make_float4(acc[6],acc[7],acc[8],acc[9]);
  *(float4*)(Cp + ((size_t)bk*LL + j)*4) = make_float4(acc[10],acc[11],acc[12],acc[13]);
}

// ---------------- K5: chunked selective scan (512 thr, chunk 16, in-kernel delta) ----------------
#define CHUNK 16
#define NTH   512
__global__ __launch_bounds__(512, 6) void k_scan(
    const float* __restrict__ seq,  const float* __restrict__ draw,
    const float* __restrict__ Bp,   const float* __restrict__ Cp,
    const float* __restrict__ dtw,  const float* __restrict__ dtb,
    const float* __restrict__ Alogs,const float* __restrict__ Dsp,
    float* __restrict__ y0, float* __restrict__ y1)
{
  const int gid = blockIdx.x;
  const int d = gid % DI;
  const int k = (gid / DI) % KD;
  const int b = gid / (DI*KD);
  const int c = threadIdx.x;
  const int kd = k*DI + d;
  float A[NS];
  #pragma unroll
  for (int n=0;n<NS;n++) A[n] = -__expf(Alogs[kd*NS+n]);
  float dwv[RK];
  #pragma unroll
  for (int r=0;r<RK;r++) dwv[r] = dtw[kd*RK+r];
  const float bias = dtb[kd];
  const float Dv   = Dsp[kd];
  const float* sq = seq + ((size_t)b*DI + d)*LL;
  const int bk = b*KD + k;
  const float* drb = draw + (size_t)bk*LL*6;
  const float4* Bb = (const float4*)(Bp + (size_t)bk*LL*4);
  const float4* Cb = (const float4*)(Cp + (size_t)bk*LL*4);

  __shared__ float4 sP4[NTH];          // 8 KB
  __shared__ float4 sH4[NTH];          // 8 KB
  __shared__ float ly[LL + (LL>>5)];   // 33.8 KB

  float de[CHUNK];
  float hP[NS], hh[NS];
  #pragma unroll
  for (int n=0;n<NS;n++){ hP[n]=1.f; hh[n]=0.f; }
  const int l0 = c*CHUNK;

  // Phase A: local chunk scan with zero init; compute & cache delta
  #pragma unroll
  for (int i=0;i<CHUNK;i++){
    int l = l0 + i;
    int j = k ? (LL-1-l) : l;
    const float2* drp = (const float2*)(drb + (size_t)j*6);
    float2 a0 = drp[0], a1 = drp[1], a2 = drp[2];
    float acc = bias + dwv[0]*a0.x + dwv[1]*a0.y + dwv[2]*a1.x
                     + dwv[3]*a1.y + dwv[4]*a2.x + dwv[5]*a2.y;
    float deltav = (acc > 20.f) ? acc : __logf(1.f + __expf(acc));
    de[i] = deltav;
    float xv = sq[j];
    float du = deltav*xv;
    const float4 Bv = Bb[j];
    #pragma unroll
    for (int n=0;n<NS;n++){
      float dA = __expf(deltav*A[n]);
      float Bn = (n==0)?Bv.x:(n==1)?Bv.y:(n==2)?Bv.z:Bv.w;
      hh[n] = fmaf(dA, hh[n], du*Bn);
      hP[n] *= dA;
    }
  }
  float4 a4 = make_float4(hP[0],hP[1],hP[2],hP[3]);
  float4 h4 = make_float4(hh[0],hh[1],hh[2],hh[3]);
  sP4[c] = a4; sH4[c] = h4;
  __syncthreads();

  // Hillis-Steele inclusive scan over 512 chunk carries
  for (int s=1; s<NTH; s<<=1){
    float4 ao, ho;
    const bool act = (c >= s);
    if (act){ ao = sP4[c-s]; ho = sH4[c-s]; }
    __syncthreads();
    if (act){
      h4.x = fmaf(a4.x, ho.x, h4.x); a4.x *= ao.x;
      h4.y = fmaf(a4.y, ho.y, h4.y); a4.y *= ao.y;
      h4.z = fmaf(a4.z, ho.z, h4.z); a4.z *= ao.z;
      h4.w = fmaf(a4.w, ho.w, h4.w); a4.w *= ao.w;
      sP4[c] = a4; sH4[c] = h4;
    }
    __syncthreads();
  }
  float4 hf = (c > 0) ? sH4[c-1] : make_float4(0.f,0.f,0.f,0.f);
  float h[NS];
  h[0]=hf.x; h[1]=hf.y; h[2]=hf.z; h[3]=hf.w;

  // Phase B: re-scan with correct init, emit y into swizzled LDS
  #pragma unroll
  for (int i=0;i<CHUNK;i++){
    int l = l0 + i;
    int j = k ? (LL-1-l) : l;
    float deltav = de[i];
    float xv = sq[j];
    float du = deltav*xv;
    float yv = Dv*xv;
    const float4 Bv = Bb[j];
    const float4 Cv = Cb[j];
    #pragma unroll
    for (int n=0;n<NS;n++){
      float dA = __expf(deltav*A[n]);
      float Bn = (n==0)?Bv.x:(n==1)?Bv.y:(n==2)?Bv.z:Bv.w;
      float Cn = (n==0)?Cv.x:(n==1)?Cv.y:(n==2)?Cv.z:Cv.w;
      h[n] = fmaf(dA, h[n], du*Bn);
      yv = fmaf(Cn, h[n], yv);
    }
    ly[j + (j>>5)] = yv;
  }
  __syncthreads();

  // coalesced float4 flush
  float* yo = (k ? y1 : y0) + ((size_t)b*DI + d)*LL;
  #pragma unroll
  for (int it=0; it<4; it++){
    int p = it*2048 + c*4;
    int sw = p >> 5;
    float4 v;
    v.x = ly[p   + sw];
    v.y = ly[p+1 + sw];
    v.z = ly[p+2 + sw];
    v.w = ly[p+3 + sw];
    *(float4*)(yo + p) = v;
  }
}

// ---------------- K6: merge + LayerNorm + SE scale -> yln[B,L,DI] ----------------
__global__ __launch_bounds__(256) void k_ln(
    const float* __restrict__ y0, const float* __restrict__ y1,
    const float* __restrict__ ln1g, const float* __restrict__ ln1b,
    const float* __restrict__ ln2g, const float* __restrict__ ln2b,
    const float* __restrict__ ex, float* __restrict__ yln)
{
  const int b  = blockIdx.y;
  const int j0 = blockIdx.x*64;
  __shared__ float v[DI][65];
  __shared__ float ps1[4][64], ps2[4][64];
  __shared__ float mu[64], rs[64];
  const int tid = threadIdx.x;
  const int jl = tid & 63, ds = tid >> 6;
  const float* p0 = y0 + (size_t)b*DI*LL + j0;
  const float* p1 = y1 + (size_t)b*DI*LL + j0;
  for (int it=0; it<48; it++){
    int d = ds*48 + it;
    v[d][jl] = p0[(size_t)d*LL + jl] + p1[(size_t)d*LL + jl];
  }
  __syncthreads();
  float s1=0.f, s2=0.f;
  for (int it=0; it<48; it++){
    float x = v[ds*48+it][jl];
    s1 += x; s2 += x*x;
  }
  ps1[ds][jl]=s1; ps2[ds][jl]=s2;
  __syncthreads();
  if (tid < 64){
    float t1 = ps1[0][tid]+ps1[1][tid]+ps1[2][tid]+ps1[3][tid];
    float t2 = ps2[0][tid]+ps2[1][tid]+ps2[2][tid]+ps2[3][tid];
    float m  = t1*(1.f/DI);
    float var= t2*(1.f/DI) - m*m;
    mu[tid]=m; rs[tid]=rsqrtf(var + 1e-5f);
  }
  __syncthreads();
  const int mod = (j0 >= HW) ? 1 : 0;
  const float* g  = mod? ln2g:ln1g;
  const float* bb = mod? ln2b:ln1b;
  const float* exm = ex + ((size_t)mod*B_ + b)*DI;
  for (int it=0; it<48; it++){
    int idx = it*256 + tid;
    int j = idx / DI;
    int d = idx - j*DI;
    float x = v[d][j];
    float o = (x - mu[j])*rs[j]*g[d] + bb[d];
    o *= exm[d];
    yln[((size_t)b*LL + j0 + j)*DI + d] = o;
  }
}

// ---------------- K7: output projection (LDS-W, register-blocked) ----------------
#define TMO 32
__global__ __launch_bounds__(128) void k_out(
    const float* __restrict__ yln, const float* __restrict__ Wo, float* __restrict__ out)
{
  __shared__ float lsW[DM*68];
  const int bid  = blockIdx.x;          // 0..255
  const int row0 = bid * TMO;           // global row = b*HW + hw
  const int b    = row0 >> 12;
  const int hw0  = row0 & (HW-1);
  const int tid  = threadIdx.x;
  const int cg = tid & 31, slot = tid >> 5;   // 4 slots
  const int r0 = slot * 8;                    // 8 rows per thread
  float acc[8][3];
  #pragma unroll
  for (int i=0;i<8;i++)
    #pragma unroll
    for (int q=0;q<3;q++) acc[i][q]=0.f;

  for (int c=0;c<6;c++){
    for (int t=tid; t<DM*64; t+=128){
      int dm = t>>6, kkl = t&63;
      lsW[dm*68 + kkl] = Wo[(size_t)dm*384 + c*64 + kkl];
    }
    __syncthreads();
    const float* xb = yln + ((size_t)b*LL + ((c<3)? hw0 : HW+hw0) + r0)*DI
                          + ((c<3)? c*64 : (c-3)*64);
    for (int kk4=0; kk4<16; kk4++){
      float4 xv[8];
      #pragma unroll
      for (int i=0;i<8;i++) xv[i] = *(const float4*)(xb + (size_t)i*DI + kk4*4);
      #pragma unroll
      for (int q=0;q<3;q++){
        const float4 wv = *(const float4*)(&lsW[(cg+32*q)*68 + kk4*4]);
        #pragma unroll
        for (int i=0;i<8;i++){
          acc[i][q] = fmaf(xv[i].x, wv.x, acc[i][q]);
          acc[i][q] = fmaf(xv[i].y, wv.y, acc[i][q]);
          acc[i][q] = fmaf(xv[i].z, wv.z, acc[i][q]);
          acc[i][q] = fmaf(xv[i].w, wv.w, acc[i][q]);
        }
      }
    }
    __syncthreads();
  }
  #pragma unroll
  for (int i=0;i<8;i++){
    float* ob = out + (size_t)(row0 + r0 + i)*DM;
    #pragma unroll
    for (int q=0;q<3;q++) ob[cg + 32*q] = acc[i][q];
  }
}

// ---------------- launch ----------------
extern "C" void kernel_launch(void* const* d_in, const int* in_sizes, int n_in,
                              void* d_out, int out_size, void* d_ws, size_t ws_size,
                              hipStream_t stream) {
  const float* x_rgb      = (const float*)d_in[0];
  const float* x_e        = (const float*)d_in[1];
  const float* in_proj_w  = (const float*)d_in[2];
  const float* in_proj_xw = (const float*)d_in[3];
  const float* conv_w     = (const float*)d_in[4];
  const float* conv_b     = (const float*)d_in[5];
  const float* conv_xw    = (const float*)d_in[6];
  const float* conv_xb    = (const float*)d_in[7];
  const float* xpw        = (const float*)d_in[8];
  const float* dtw        = (const float*)d_in[9];
  const float* dtb        = (const float*)d_in[10];
  const float* A_logs     = (const float*)d_in[11];
  const float* Ds         = (const float*)d_in[12];
  const float* ln1_g      = (const float*)d_in[13];
  const float* ln1_b      = (const float*)d_in[14];
  const float* ln2_g      = (const float*)d_in[15];
  const float* ln2_b      = (const float*)d_in[16];
  const float* out_proj_w = (const float*)d_in[17];
  const float* fc1_w1     = (const float*)d_in[18];
  const float* fc1_w2     = (const float*)d_in[19];
  const float* fc2_w1     = (const float*)d_in[20];
  const float* fc2_w2     = (const float*)d_in[21];

  float* ws = (float*)d_ws;
  // layout (floats):
  //  [0, 3145728)        xr_t/xe_t -> y0   (dead after k_conv; scan overwrites with y0)
  //  [3145728, 6291456)  seq -> yln (alias; seq dead after k_scan)
  //  [6291456, 9437184)  y1
  //  [9437184, ...)      draw, Bp, Cp, sr, ex
  float* xr_t = ws;                        // 1,572,864
  float* xe_t = ws + 1572864;              // 1,572,864
  float* y0   = ws;                        // 3,145,728 (alias)
  float* seq  = ws + 3145728;              // 3,145,728
  float* yln  = seq;                       // alias
  float* y1   = ws + 6291456;              // 3,145,728
  float* draw = ws + 9437184;              //   196,608
  float* Bp   = ws + 9633792;              //   131,072
  float* Cp   = ws + 9764864;              //   131,072
  float* sr   = ws + 9895936;              //       768
  float* ex   = ws + 9896704;              //       768

  k_zero  <<<dim3(3), 256, 0, stream>>>(sr, 768);
  k_inproj<<<dim3(HW/64, B_, 2), 256, 0, stream>>>(x_rgb, x_e, in_proj_w, in_proj_xw, xr_t, xe_t, sr);
  k_conv  <<<dim3(HW/256, DI, B_*2), 256, 0, stream>>>(xr_t, xe_t, conv_w, conv_b, conv_xw, conv_xb, seq);
  k_se    <<<dim3(B_, 2), DI, 0, stream>>>(sr, fc1_w1, fc1_w2, fc2_w1, fc2_w2, ex);
  k_proj  <<<dim3(LL/256, KD, B_), 256, 0, stream>>>(seq, xpw, draw, Bp, Cp);
  k_scan  <<<dim3(B_*KD*DI), NTH, 0, stream>>>(seq, draw, Bp, Cp, dtw, dtb, A_logs, Ds, y0, y1);
  k_ln    <<<dim3(LL/64, B_), 256, 0, stream>>>(y0, y1, ln1_g, ln1_b, ln2_g, ln2_b, ex, yln);
  k_out   <<<dim3(8192/TMO), 128, 0, stream>>>(yln, out_proj_w, (float*)d_out);
}

// Round 6
// 246.641 us; speedup vs baseline: 1.5657x; 1.5657x over previous
//
#include <hip/hip_runtime.h>
#include <math.h>

#define B_  2
#define H_  64
#define W_  64
#define HW  4096
#define DM  96
#define DI  192
#define NS  4
#define RK  6
#define KD  2
#define LL  8192   // 2*HW

__device__ __forceinline__ float sigmoidf_(float x){ return 1.f/(1.f+__expf(-x)); }

// ---------------- K0: zero the sr accumulator ----------------
__global__ void k_zero(float* __restrict__ p, int n){
  int i = blockIdx.x*256 + threadIdx.x;
  if (i < n) p[i] = 0.f;
}

// ---------------- K1: input projections -> channel-major [B,DI,HW] + fused channel sums ----------------
__global__ __launch_bounds__(256) void k_inproj(
    const float* __restrict__ xrgb, const float* __restrict__ xe,
    const float* __restrict__ wr,   const float* __restrict__ we,
    float* __restrict__ xrt, float* __restrict__ xet, float* __restrict__ sr)
{
  __shared__ float lsW[DI*100];
  __shared__ float lsum[DI];
  const int mod = blockIdx.z, b = blockIdx.y;
  const int hw0 = blockIdx.x * 64;
  const float* x  = mod ? xe  : xrgb;
  const float* Wp = mod ? we  : wr;
  float* out      = mod ? xet : xrt;
  const int tid = threadIdx.x;
  for (int t = tid; t < DI*DM; t += 256){
    int di = t / DM, kk = t - di*DM;
    lsW[di*100 + kk] = Wp[t];
  }
  if (tid < DI) lsum[tid] = 0.f;
  const int cg = tid & 31, slot = tid >> 5;   // 8 slots
  const int r0 = slot * 8;
  const float* xb = x + ((size_t)(b*HW) + hw0 + r0)*DM;
  float acc[8][6];
  #pragma unroll
  for (int i=0;i<8;i++)
    #pragma unroll
    for (int q=0;q<6;q++) acc[i][q]=0.f;
  __syncthreads();
  for (int kk4=0; kk4<DM/4; kk4++){
    float4 xv[8];
    #pragma unroll
    for (int i=0;i<8;i++) xv[i] = *(const float4*)(xb + (size_t)i*DM + kk4*4);
    #pragma unroll
    for (int q=0;q<6;q++){
      const float4 wv = *(const float4*)(&lsW[(cg+32*q)*100 + kk4*4]);
      #pragma unroll
      for (int i=0;i<8;i++){
        acc[i][q] = fmaf(xv[i].x, wv.x, acc[i][q]);
        acc[i][q] = fmaf(xv[i].y, wv.y, acc[i][q]);
        acc[i][q] = fmaf(xv[i].z, wv.z, acc[i][q]);
        acc[i][q] = fmaf(xv[i].w, wv.w, acc[i][q]);
      }
    }
  }
  #pragma unroll
  for (int q=0;q<6;q++){
    int di = cg + 32*q;
    float* ob = out + ((size_t)(b*DI + di))*HW + hw0 + r0;
    float ps = 0.f;
    #pragma unroll
    for (int i=0;i<8;i++){ ob[i] = acc[i][q]; ps += acc[i][q]; }
    atomicAdd(&lsum[di], ps);
  }
  __syncthreads();
  if (tid < DI) atomicAdd(&sr[((size_t)mod*B_ + b)*DI + tid], lsum[tid]);
}

// ---------------- K2: depthwise 3x3 conv + SiLU -> seq[B,DI,2HW] ----------------
__global__ __launch_bounds__(256) void k_conv(
    const float* __restrict__ xrt, const float* __restrict__ xet,
    const float* __restrict__ cwr, const float* __restrict__ cbr,
    const float* __restrict__ cwe, const float* __restrict__ cbe,
    float* __restrict__ seq)
{
  const int z = blockIdx.z; const int b = z >> 1, mod = z & 1;
  const int d = blockIdx.y;
  const float* in = (mod? xet:xrt) + ((size_t)b*DI + d)*HW;
  const float* wp = (mod? cwe:cwr) + d*9;
  const float  bias = (mod? cbe:cbr)[d];
  const int hw = blockIdx.x*256 + threadIdx.x;
  const int y = hw >> 6, x = hw & 63;
  float w[9];
  #pragma unroll
  for (int i=0;i<9;i++) w[i]=wp[i];
  float acc = bias;
  #pragma unroll
  for (int dy=-1;dy<=1;dy++){
    int yy = y+dy;
    if (yy<0||yy>=H_) continue;
    #pragma unroll
    for (int dx=-1;dx<=1;dx++){
      int xx = x+dx;
      if (xx<0||xx>=W_) continue;
      acc += in[yy*W_+xx]*w[(dy+1)*3 + dx+1];
    }
  }
  float v = acc * sigmoidf_(acc);
  seq[((size_t)b*DI + d)*LL + mod*HW + hw] = v;
}

// ---------------- K3: squeeze-excitation MLP (sr holds channel SUMS; scale by 1/HW) ----------------
__global__ void k_se(const float* __restrict__ sr,
                     const float* __restrict__ f11, const float* __restrict__ f12,
                     const float* __restrict__ f21, const float* __restrict__ f22,
                     float* __restrict__ ex)
{
  const int b = blockIdx.x, mod = blockIdx.y;
  const float* f1 = mod? f21:f11;
  const float* f2 = mod? f22:f12;
  __shared__ float s[DI];
  __shared__ float hid[12];
  const int t = threadIdx.x;
  s[t] = sr[((size_t)mod*B_ + b)*DI + t] * (1.f/HW);
  __syncthreads();
  if (t < 12){
    float a=0.f;
    for (int dd=0; dd<DI; dd++) a += f1[t*DI+dd]*s[dd];
    hid[t] = a * sigmoidf_(a);
  }
  __syncthreads();
  float a=0.f;
  #pragma unroll
  for (int h=0; h<12; h++) a += f2[t*12+h]*hid[h];
  ex[((size_t)mod*B_ + b)*DI + t] = sigmoidf_(a);
}

// ---------------- K4: x_proj of seq -> SoA planes P[bk][14][LL] ----------------
// planes 0..5 = dt-rank, 6..9 = B, 10..13 = C
__global__ __launch_bounds__(256) void k_proj(
    const float* __restrict__ seq, const float* __restrict__ xpw,
    float* __restrict__ P)
{
  __shared__ float lw[14*DI];
  const int b = blockIdx.z, k = blockIdx.y;
  const int j = blockIdx.x*256 + threadIdx.x;
  for (int t = threadIdx.x; t < 14*DI; t += 256) lw[t] = xpw[(size_t)k*14*DI + t];
  __syncthreads();
  float acc[14];
  #pragma unroll
  for (int c=0;c<14;c++) acc[c]=0.f;
  const float* sp = seq + (size_t)b*DI*LL + j;
  for (int dd=0; dd<DI; dd++){
    float s = sp[(size_t)dd*LL];
    #pragma unroll
    for (int cc=0; cc<14; cc++) acc[cc] = fmaf(lw[cc*DI+dd], s, acc[cc]);
  }
  const int bk = b*KD + k;
  float* Pb = P + (size_t)bk*14*LL;
  #pragma unroll
  for (int cc=0; cc<14; cc++) Pb[(size_t)cc*LL + j] = acc[cc];
}

// ---------------- K5: chunked selective scan (SoA float4 loads) ----------------
#define CHUNK 32
#define NCH   256
__global__ __launch_bounds__(256, 3) void k_scan(
    const float* __restrict__ seq,  const float* __restrict__ P,
    const float* __restrict__ dtw,  const float* __restrict__ dtb,
    const float* __restrict__ Alogs,const float* __restrict__ Dsp,
    float* __restrict__ y0, float* __restrict__ y1)
{
  const int gid = blockIdx.x;
  const int d = gid % DI;
  const int k = (gid / DI) % KD;
  const int b = gid / (DI*KD);
  const int c = threadIdx.x;
  const int kd = k*DI + d;
  float A[NS];
  #pragma unroll
  for (int n=0;n<NS;n++) A[n] = -__expf(Alogs[kd*NS+n]);
  float dwv[RK];
  #pragma unroll
  for (int r=0;r<RK;r++) dwv[r] = dtw[kd*RK+r];
  const float bias = dtb[kd];
  const float Dv   = Dsp[kd];
  const float* sq = seq + ((size_t)b*DI + d)*LL;
  const int bk = b*KD + k;
  const float* Pb = P + (size_t)bk*14*LL;
  // chunk occupies j in [jlo, jlo+CHUNK); l-order is ascending j for k=0, descending for k=1
  const int jlo = k ? (LL - (c+1)*CHUNK) : (c*CHUNK);

  __shared__ float4 sP4[NCH];          // 4 KB
  __shared__ float4 sH4[NCH];          // 4 KB
  __shared__ float ly[LL + (LL>>5)];   // 33.8 KB

  float de[CHUNK];
  float hP[NS], hh[NS];
  #pragma unroll
  for (int n=0;n<NS;n++){ hP[n]=1.f; hh[n]=0.f; }

#define GETC(v_, s_) ((s_)==0?(v_).x:((s_)==1?(v_).y:((s_)==2?(v_).z:(v_).w)))
#define STEPA(s_, i_) { \
      float accv = bias + dwv[0]*GETC(fd0,s_) + dwv[1]*GETC(fd1,s_) \
                 + dwv[2]*GETC(fd2,s_) + dwv[3]*GETC(fd3,s_) \
                 + dwv[4]*GETC(fd4,s_) + dwv[5]*GETC(fd5,s_); \
      float deltav = (accv > 20.f) ? accv : __logf(1.f + __expf(accv)); \
      de[i_] = deltav; \
      float du = deltav * GETC(fx,s_); \
      float dA0=__expf(deltav*A[0]), dA1=__expf(deltav*A[1]); \
      float dA2=__expf(deltav*A[2]), dA3=__expf(deltav*A[3]); \
      hh[0]=fmaf(dA0,hh[0],du*GETC(fB0,s_)); hP[0]*=dA0; \
      hh[1]=fmaf(dA1,hh[1],du*GETC(fB1,s_)); hP[1]*=dA1; \
      hh[2]=fmaf(dA2,hh[2],du*GETC(fB2,s_)); hP[2]*=dA2; \
      hh[3]=fmaf(dA3,hh[3],du*GETC(fB3,s_)); hP[3]*=dA3; }

  // Phase A: local chunk scan with zero init; cache delta
  #pragma unroll
  for (int g=0; g<CHUNK/4; g++){
    const int gb = jlo + 4*g;
    const float4 fd0 = *(const float4*)(Pb + 0*(size_t)LL + gb);
    const float4 fd1 = *(const float4*)(Pb + 1*(size_t)LL + gb);
    const float4 fd2 = *(const float4*)(Pb + 2*(size_t)LL + gb);
    const float4 fd3 = *(const float4*)(Pb + 3*(size_t)LL + gb);
    const float4 fd4 = *(const float4*)(Pb + 4*(size_t)LL + gb);
    const float4 fd5 = *(const float4*)(Pb + 5*(size_t)LL + gb);
    const float4 fx  = *(const float4*)(sq + gb);
    const float4 fB0 = *(const float4*)(Pb + 6*(size_t)LL + gb);
    const float4 fB1 = *(const float4*)(Pb + 7*(size_t)LL + gb);
    const float4 fB2 = *(const float4*)(Pb + 8*(size_t)LL + gb);
    const float4 fB3 = *(const float4*)(Pb + 9*(size_t)LL + gb);
    if (!k){ STEPA(0,4*g+0) STEPA(1,4*g+1) STEPA(2,4*g+2) STEPA(3,4*g+3) }
    else   { STEPA(3,4*g+0) STEPA(2,4*g+1) STEPA(1,4*g+2) STEPA(0,4*g+3) }
  }

  float4 a4 = make_float4(hP[0],hP[1],hP[2],hP[3]);
  float4 h4 = make_float4(hh[0],hh[1],hh[2],hh[3]);
  sP4[c] = a4; sH4[c] = h4;
  __syncthreads();

  // Hillis-Steele inclusive scan over chunk carries
  for (int s=1; s<NCH; s<<=1){
    float4 ao, ho;
    const bool act = (c >= s);
    if (act){ ao = sP4[c-s]; ho = sH4[c-s]; }
    __syncthreads();
    if (act){
      h4.x = fmaf(a4.x, ho.x, h4.x); a4.x *= ao.x;
      h4.y = fmaf(a4.y, ho.y, h4.y); a4.y *= ao.y;
      h4.z = fmaf(a4.z, ho.z, h4.z); a4.z *= ao.z;
      h4.w = fmaf(a4.w, ho.w, h4.w); a4.w *= ao.w;
      sP4[c] = a4; sH4[c] = h4;
    }
    __syncthreads();
  }
  float4 hf = (c > 0) ? sH4[c-1] : make_float4(0.f,0.f,0.f,0.f);
  float h[NS];
  h[0]=hf.x; h[1]=hf.y; h[2]=hf.z; h[3]=hf.w;

#define STEPB(s_, i_) { \
      float deltav = de[i_]; \
      float xv = GETC(fx,s_); \
      float du = deltav*xv; \
      float yv = Dv*xv; \
      float dA0=__expf(deltav*A[0]), dA1=__expf(deltav*A[1]); \
      float dA2=__expf(deltav*A[2]), dA3=__expf(deltav*A[3]); \
      h[0]=fmaf(dA0,h[0],du*GETC(fB0,s_)); yv=fmaf(GETC(fC0,s_),h[0],yv); \
      h[1]=fmaf(dA1,h[1],du*GETC(fB1,s_)); yv=fmaf(GETC(fC1,s_),h[1],yv); \
      h[2]=fmaf(dA2,h[2],du*GETC(fB2,s_)); yv=fmaf(GETC(fC2,s_),h[2],yv); \
      h[3]=fmaf(dA3,h[3],du*GETC(fB3,s_)); yv=fmaf(GETC(fC3,s_),h[3],yv); \
      const int jj = gb + s_; \
      ly[jj + (jj>>5)] = yv; }

  // Phase B: re-scan with correct init, emit y into swizzled LDS
  #pragma unroll
  for (int g=0; g<CHUNK/4; g++){
    const int gb = jlo + 4*g;
    const float4 fx  = *(const float4*)(sq + gb);
    const float4 fB0 = *(const float4*)(Pb + 6*(size_t)LL + gb);
    const float4 fB1 = *(const float4*)(Pb + 7*(size_t)LL + gb);
    const float4 fB2 = *(const float4*)(Pb + 8*(size_t)LL + gb);
    const float4 fB3 = *(const float4*)(Pb + 9*(size_t)LL + gb);
    const float4 fC0 = *(const float4*)(Pb + 10*(size_t)LL + gb);
    const float4 fC1 = *(const float4*)(Pb + 11*(size_t)LL + gb);
    const float4 fC2 = *(const float4*)(Pb + 12*(size_t)LL + gb);
    const float4 fC3 = *(const float4*)(Pb + 13*(size_t)LL + gb);
    if (!k){ STEPB(0,4*g+0) STEPB(1,4*g+1) STEPB(2,4*g+2) STEPB(3,4*g+3) }
    else   { STEPB(3,4*g+0) STEPB(2,4*g+1) STEPB(1,4*g+2) STEPB(0,4*g+3) }
  }
  __syncthreads();

  // coalesced float4 flush
  float* yo = (k ? y1 : y0) + ((size_t)b*DI + d)*LL;
  #pragma unroll
  for (int it=0; it<8; it++){
    int p = it*1024 + c*4;
    int sw = p >> 5;
    float4 v;
    v.x = ly[p   + sw];
    v.y = ly[p+1 + sw];
    v.z = ly[p+2 + sw];
    v.w = ly[p+3 + sw];
    *(float4*)(yo + p) = v;
  }
}

// ---------------- K6: merge + LayerNorm + SE scale -> yln[B,L,DI] ----------------
__global__ __launch_bounds__(256) void k_ln(
    const float* __restrict__ y0, const float* __restrict__ y1,
    const float* __restrict__ ln1g, const float* __restrict__ ln1b,
    const float* __restrict__ ln2g, const float* __restrict__ ln2b,
    const float* __restrict__ ex, float* __restrict__ yln)
{
  const int b  = blockIdx.y;
  const int j0 = blockIdx.x*64;
  __shared__ float v[DI][65];
  __shared__ float ps1[4][64], ps2[4][64];
  __shared__ float mu[64], rs[64];
  const int tid = threadIdx.x;
  const int jl = tid & 63, ds = tid >> 6;
  const float* p0 = y0 + (size_t)b*DI*LL + j0;
  const float* p1 = y1 + (size_t)b*DI*LL + j0;
  for (int it=0; it<48; it++){
    int d = ds*48 + it;
    v[d][jl] = p0[(size_t)d*LL + jl] + p1[(size_t)d*LL + jl];
  }
  __syncthreads();
  float s1=0.f, s2=0.f;
  for (int it=0; it<48; it++){
    float x = v[ds*48+it][jl];
    s1 += x; s2 += x*x;
  }
  ps1[ds][jl]=s1; ps2[ds][jl]=s2;
  __syncthreads();
  if (tid < 64){
    float t1 = ps1[0][tid]+ps1[1][tid]+ps1[2][tid]+ps1[3][tid];
    float t2 = ps2[0][tid]+ps2[1][tid]+ps2[2][tid]+ps2[3][tid];
    float m  = t1*(1.f/DI);
    float var= t2*(1.f/DI) - m*m;
    mu[tid]=m; rs[tid]=rsqrtf(var + 1e-5f);
  }
  __syncthreads();
  const int mod = (j0 >= HW) ? 1 : 0;
  const float* g  = mod? ln2g:ln1g;
  const float* bb = mod? ln2b:ln1b;
  const float* exm = ex + ((size_t)mod*B_ + b)*DI;
  for (int it=0; it<48; it++){
    int idx = it*256 + tid;
    int j = idx / DI;
    int d = idx - j*DI;
    float x = v[d][j];
    float o = (x - mu[j])*rs[j]*g[d] + bb[d];
    o *= exm[d];
    yln[((size_t)b*LL + j0 + j)*DI + d] = o;
  }
}

// ---------------- K7: output projection (LDS-W, register-blocked) ----------------
#define TMO 32
__global__ __launch_bounds__(128) void k_out(
    const float* __restrict__ yln, const float* __restrict__ Wo, float* __restrict__ out)
{
  __shared__ float lsW[DM*68];
  const int bid  = blockIdx.x;          // 0..255
  const int row0 = bid * TMO;           // global row = b*HW + hw
  const int b    = row0 >> 12;
  const int hw0  = row0 & (HW-1);
  const int tid  = threadIdx.x;
  const int cg = tid & 31, slot = tid >> 5;   // 4 slots
  const int r0 = slot * 8;                    // 8 rows per thread
  float acc[8][3];
  #pragma unroll
  for (int i=0;i<8;i++)
    #pragma unroll
    for (int q=0;q<3;q++) acc[i][q]=0.f;

  for (int c=0;c<6;c++){
    for (int t=tid; t<DM*64; t+=128){
      int dm = t>>6, kkl = t&63;
      lsW[dm*68 + kkl] = Wo[(size_t)dm*384 + c*64 + kkl];
    }
    __syncthreads();
    const float* xb = yln + ((size_t)b*LL + ((c<3)? hw0 : HW+hw0) + r0)*DI
                          + ((c<3)? c*64 : (c-3)*64);
    for (int kk4=0; kk4<16; kk4++){
      float4 xv[8];
      #pragma unroll
      for (int i=0;i<8;i++) xv[i] = *(const float4*)(xb + (size_t)i*DI + kk4*4);
      #pragma unroll
      for (int q=0;q<3;q++){
        const float4 wv = *(const float4*)(&lsW[(cg+32*q)*68 + kk4*4]);
        #pragma unroll
        for (int i=0;i<8;i++){
          acc[i][q] = fmaf(xv[i].x, wv.x, acc[i][q]);
          acc[i][q] = fmaf(xv[i].y, wv.y, acc[i][q]);
          acc[i][q] = fmaf(xv[i].z, wv.z, acc[i][q]);
          acc[i][q] = fmaf(xv[i].w, wv.w, acc[i][q]);
        }
      }
    }
    __syncthreads();
  }
  #pragma unroll
  for (int i=0;i<8;i++){
    float* ob = out + (size_t)(row0 + r0 + i)*DM;
    #pragma unroll
    for (int q=0;q<3;q++) ob[cg + 32*q] = acc[i][q];
  }
}

// ---------------- launch ----------------
extern "C" void kernel_launch(void* const* d_in, const int* in_sizes, int n_in,
                              void* d_out, int out_size, void* d_ws, size_t ws_size,
                              hipStream_t stream) {
  const float* x_rgb      = (const float*)d_in[0];
  const float* x_e        = (const float*)d_in[1];
  const float* in_proj_w  = (const float*)d_in[2];
  const float* in_proj_xw = (const float*)d_in[3];
  const float* conv_w     = (const float*)d_in[4];
  const float* conv_b     = (const float*)d_in[5];
  const float* conv_xw    = (const float*)d_in[6];
  const float* conv_xb    = (const float*)d_in[7];
  const float* xpw        = (const float*)d_in[8];
  const float* dtw        = (const float*)d_in[9];
  const float* dtb        = (const float*)d_in[10];
  const float* A_logs     = (const float*)d_in[11];
  const float* Ds         = (const float*)d_in[12];
  const float* ln1_g      = (const float*)d_in[13];
  const float* ln1_b      = (const float*)d_in[14];
  const float* ln2_g      = (const float*)d_in[15];
  const float* ln2_b      = (const float*)d_in[16];
  const float* out_proj_w = (const float*)d_in[17];
  const float* fc1_w1     = (const float*)d_in[18];
  const float* fc1_w2     = (const float*)d_in[19];
  const float* fc2_w1     = (const float*)d_in[20];
  const float* fc2_w2     = (const float*)d_in[21];

  float* ws = (float*)d_ws;
  // layout (floats):
  //  [0, 3145728)        xr_t/xe_t -> y0 (xr/xe dead after k_conv; scan overwrites with y0)
  //  [3145728, 6291456)  seq -> yln (alias; seq dead after k_scan)
  //  [6291456, 9437184)  y1
  //  [9437184, 9895936)  P (SoA planes, 4*14*8192)
  //  [9895936, ...)      sr, ex
  float* xr_t = ws;                        // 1,572,864
  float* xe_t = ws + 1572864;              // 1,572,864
  float* y0   = ws;                        // 3,145,728 (alias)
  float* seq  = ws + 3145728;              // 3,145,728
  float* yln  = seq;                       // alias
  float* y1   = ws + 6291456;              // 3,145,728
  float* P    = ws + 9437184;              //   458,752
  float* sr   = ws + 9895936;              //       768
  float* ex   = ws + 9896704;              //       768

  k_zero  <<<dim3(3), 256, 0, stream>>>(sr, 768);
  k_inproj<<<dim3(HW/64, B_, 2), 256, 0, stream>>>(x_rgb, x_e, in_proj_w, in_proj_xw, xr_t, xe_t, sr);
  k_conv  <<<dim3(HW/256, DI, B_*2), 256, 0, stream>>>(xr_t, xe_t, conv_w, conv_b, conv_xw, conv_xb, seq);
  k_se    <<<dim3(B_, 2), DI, 0, stream>>>(sr, fc1_w1, fc1_w2, fc2_w1, fc2_w2, ex);
  k_proj  <<<dim3(LL/256, KD, B_), 256, 0, stream>>>(seq, xpw, P);
  k_scan  <<<dim3(B_*KD*DI), NCH, 0, stream>>>(seq, P, dtw, dtb, A_logs, Ds, y0, y1);
  k_ln    <<<dim3(LL/64, B_), 256, 0, stream>>>(y0, y1, ln1_g, ln1_b, ln2_g, ln2_b, ex, yln);
  k_out   <<<dim3(8192/TMO), 128, 0, stream>>>(yln, out_proj_w, (float*)d_out);
}

// Round 7
// 202.625 us; speedup vs baseline: 1.9058x; 1.2172x over previous
//
#include <hip/hip_runtime.h>
#include <math.h>

#define B_  2
#define H_  64
#define W_  64
#define HW  4096
#define DM  96
#define DI  192
#define NS  4
#define RK  6
#define KD  2
#define LL  8192   // 2*HW

__device__ __forceinline__ float sigmoidf_(float x){ return 1.f/(1.f+__expf(-x)); }

// ---------------- K0: zero the sr accumulator ----------------
__global__ void k_zero(float* __restrict__ p, int n){
  int i = blockIdx.x*256 + threadIdx.x;
  if (i < n) p[i] = 0.f;
}

// ---------------- K1: input projections -> channel-major [B,DI,HW] + fused channel sums ----------------
__global__ __launch_bounds__(256) void k_inproj(
    const float* __restrict__ xrgb, const float* __restrict__ xe,
    const float* __restrict__ wr,   const float* __restrict__ we,
    float* __restrict__ xrt, float* __restrict__ xet, float* __restrict__ sr)
{
  __shared__ float lsW[DI*100];
  __shared__ float lsum[DI];
  const int mod = blockIdx.z, b = blockIdx.y;
  const int hw0 = blockIdx.x * 64;
  const float* x  = mod ? xe  : xrgb;
  const float* Wp = mod ? we  : wr;
  float* out      = mod ? xet : xrt;
  const int tid = threadIdx.x;
  for (int t = tid; t < DI*DM; t += 256){
    int di = t / DM, kk = t - di*DM;
    lsW[di*100 + kk] = Wp[t];
  }
  if (tid < DI) lsum[tid] = 0.f;
  const int cg = tid & 31, slot = tid >> 5;   // 8 slots
  const int r0 = slot * 8;
  const float* xb = x + ((size_t)(b*HW) + hw0 + r0)*DM;
  float acc[8][6];
  #pragma unroll
  for (int i=0;i<8;i++)
    #pragma unroll
    for (int q=0;q<6;q++) acc[i][q]=0.f;
  __syncthreads();
  for (int kk4=0; kk4<DM/4; kk4++){
    float4 xv[8];
    #pragma unroll
    for (int i=0;i<8;i++) xv[i] = *(const float4*)(xb + (size_t)i*DM + kk4*4);
    #pragma unroll
    for (int q=0;q<6;q++){
      const float4 wv = *(const float4*)(&lsW[(cg+32*q)*100 + kk4*4]);
      #pragma unroll
      for (int i=0;i<8;i++){
        acc[i][q] = fmaf(xv[i].x, wv.x, acc[i][q]);
        acc[i][q] = fmaf(xv[i].y, wv.y, acc[i][q]);
        acc[i][q] = fmaf(xv[i].z, wv.z, acc[i][q]);
        acc[i][q] = fmaf(xv[i].w, wv.w, acc[i][q]);
      }
    }
  }
  #pragma unroll
  for (int q=0;q<6;q++){
    int di = cg + 32*q;
    float* ob = out + ((size_t)(b*DI + di))*HW + hw0 + r0;
    float ps = 0.f;
    #pragma unroll
    for (int i=0;i<8;i++){ ob[i] = acc[i][q]; ps += acc[i][q]; }
    atomicAdd(&lsum[di], ps);
  }
  __syncthreads();
  if (tid < DI) atomicAdd(&sr[((size_t)mod*B_ + b)*DI + tid], lsum[tid]);
}

// ---------------- K2: depthwise 3x3 conv + SiLU -> seq[B,DI,2HW] ----------------
__global__ __launch_bounds__(256) void k_conv(
    const float* __restrict__ xrt, const float* __restrict__ xet,
    const float* __restrict__ cwr, const float* __restrict__ cbr,
    const float* __restrict__ cwe, const float* __restrict__ cbe,
    float* __restrict__ seq)
{
  const int z = blockIdx.z; const int b = z >> 1, mod = z & 1;
  const int d = blockIdx.y;
  const float* in = (mod? xet:xrt) + ((size_t)b*DI + d)*HW;
  const float* wp = (mod? cwe:cwr) + d*9;
  const float  bias = (mod? cbe:cbr)[d];
  const int hw = blockIdx.x*256 + threadIdx.x;
  const int y = hw >> 6, x = hw & 63;
  float w[9];
  #pragma unroll
  for (int i=0;i<9;i++) w[i]=wp[i];
  float acc = bias;
  #pragma unroll
  for (int dy=-1;dy<=1;dy++){
    int yy = y+dy;
    if (yy<0||yy>=H_) continue;
    #pragma unroll
    for (int dx=-1;dx<=1;dx++){
      int xx = x+dx;
      if (xx<0||xx>=W_) continue;
      acc += in[yy*W_+xx]*w[(dy+1)*3 + dx+1];
    }
  }
  float v = acc * sigmoidf_(acc);
  seq[((size_t)b*DI + d)*LL + mod*HW + hw] = v;
}

// ---------------- K3: squeeze-excitation MLP (sr holds channel SUMS; scale by 1/HW) ----------------
__global__ void k_se(const float* __restrict__ sr,
                     const float* __restrict__ f11, const float* __restrict__ f12,
                     const float* __restrict__ f21, const float* __restrict__ f22,
                     float* __restrict__ ex)
{
  const int b = blockIdx.x, mod = blockIdx.y;
  const float* f1 = mod? f21:f11;
  const float* f2 = mod? f22:f12;
  __shared__ float s[DI];
  __shared__ float hid[12];
  const int t = threadIdx.x;
  s[t] = sr[((size_t)mod*B_ + b)*DI + t] * (1.f/HW);
  __syncthreads();
  if (t < 12){
    float a=0.f;
    for (int dd=0; dd<DI; dd++) a += f1[t*DI+dd]*s[dd];
    hid[t] = a * sigmoidf_(a);
  }
  __syncthreads();
  float a=0.f;
  #pragma unroll
  for (int h=0; h<12; h++) a += f2[t*12+h]*hid[h];
  ex[((size_t)mod*B_ + b)*DI + t] = sigmoidf_(a);
}

// ---------------- K4: x_proj of seq -> SoA planes P[bk][14][LL] ----------------
// planes 0..5 = dt-rank, 6..9 = B, 10..13 = C
__global__ __launch_bounds__(256) void k_proj(
    const float* __restrict__ seq, const float* __restrict__ xpw,
    float* __restrict__ P)
{
  __shared__ float lw[14*DI];
  const int b = blockIdx.z, k = blockIdx.y;
  const int j = blockIdx.x*256 + threadIdx.x;
  for (int t = threadIdx.x; t < 14*DI; t += 256) lw[t] = xpw[(size_t)k*14*DI + t];
  __syncthreads();
  float acc[14];
  #pragma unroll
  for (int c=0;c<14;c++) acc[c]=0.f;
  const float* sp = seq + (size_t)b*DI*LL + j;
  for (int dd=0; dd<DI; dd++){
    float s = sp[(size_t)dd*LL];
    #pragma unroll
    for (int cc=0; cc<14; cc++) acc[cc] = fmaf(lw[cc*DI+dd], s, acc[cc]);
  }
  const int bk = b*KD + k;
  float* Pb = P + (size_t)bk*14*LL;
  #pragma unroll
  for (int cc=0; cc<14; cc++) Pb[(size_t)cc*LL + j] = acc[cc];
}

// ---------------- K5: tiled block scan (coalesced loads, shfl_up scan) ----------------
#define NTILE (LL/256)   // 32
__global__ __launch_bounds__(256) void k_scan(
    const float* __restrict__ seq,  const float* __restrict__ P,
    const float* __restrict__ dtw,  const float* __restrict__ dtb,
    const float* __restrict__ Alogs,const float* __restrict__ Dsp,
    float* __restrict__ y0, float* __restrict__ y1)
{
  const int gid = blockIdx.x;
  const int d = gid % DI;
  const int k = (gid / DI) % KD;
  const int b = gid / (DI*KD);
  const int t = threadIdx.x;
  const int lane = t & 63, w = t >> 6;
  const int kd = k*DI + d;
  const float A0 = -__expf(Alogs[kd*NS+0]);
  const float A1 = -__expf(Alogs[kd*NS+1]);
  const float A2 = -__expf(Alogs[kd*NS+2]);
  const float A3 = -__expf(Alogs[kd*NS+3]);
  float dwv[RK];
  #pragma unroll
  for (int r=0;r<RK;r++) dwv[r] = dtw[kd*RK+r];
  const float bias = dtb[kd];
  const float Dv   = Dsp[kd];
  const float* sq = seq + ((size_t)b*DI + d)*LL;
  const int bk = b*KD + k;
  const float* Pb = P + (size_t)bk*14*LL;
  float* yo = (k ? y1 : y0) + ((size_t)b*DI + d)*LL;

  __shared__ float wc[2][4][8];   // [buf][wave][a0..a3,h0..h3]

  float cH0=0.f, cH1=0.f, cH2=0.f, cH3=0.f;   // global running carry (h only)

  const int off = k ? (255 - t) : t;          // l-order mapped to j within tile

  // preload tile 0
  int base = k ? (LL - 256) : 0;
  int jn = base + off;
  float n0 = Pb[0*(size_t)LL + jn];
  float n1 = Pb[1*(size_t)LL + jn];
  float n2 = Pb[2*(size_t)LL + jn];
  float n3 = Pb[3*(size_t)LL + jn];
  float n4 = Pb[4*(size_t)LL + jn];
  float n5 = Pb[5*(size_t)LL + jn];
  float nx = sq[jn];
  float nB0 = Pb[6*(size_t)LL + jn];
  float nB1 = Pb[7*(size_t)LL + jn];
  float nB2 = Pb[8*(size_t)LL + jn];
  float nB3 = Pb[9*(size_t)LL + jn];
  float nC0 = Pb[10*(size_t)LL + jn];
  float nC1 = Pb[11*(size_t)LL + jn];
  float nC2 = Pb[12*(size_t)LL + jn];
  float nC3 = Pb[13*(size_t)LL + jn];

  for (int tt=0; tt<NTILE; ++tt){
    // consume prefetched regs
    const int j = jn;
    const float f0=n0,f1=n1,f2=n2,f3=n3,f4=n4,f5=n5, xv=nx;
    const float B0=nB0,B1=nB1,B2=nB2,B3=nB3;
    const float C0=nC0,C1=nC1,C2=nC2,C3=nC3;

    // issue next tile's loads (hidden under shuffle scan + barrier)
    if (tt+1 < NTILE){
      base = k ? (LL - 256*(tt+2)) : (256*(tt+1));
      jn = base + off;
      n0 = Pb[0*(size_t)LL + jn];
      n1 = Pb[1*(size_t)LL + jn];
      n2 = Pb[2*(size_t)LL + jn];
      n3 = Pb[3*(size_t)LL + jn];
      n4 = Pb[4*(size_t)LL + jn];
      n5 = Pb[5*(size_t)LL + jn];
      nx = sq[jn];
      nB0 = Pb[6*(size_t)LL + jn];
      nB1 = Pb[7*(size_t)LL + jn];
      nB2 = Pb[8*(size_t)LL + jn];
      nB3 = Pb[9*(size_t)LL + jn];
      nC0 = Pb[10*(size_t)LL + jn];
      nC1 = Pb[11*(size_t)LL + jn];
      nC2 = Pb[12*(size_t)LL + jn];
      nC3 = Pb[13*(size_t)LL + jn];
    }

    // per-position element (a, h)
    float acc = bias;
    acc = fmaf(dwv[0],f0,acc); acc = fmaf(dwv[1],f1,acc);
    acc = fmaf(dwv[2],f2,acc); acc = fmaf(dwv[3],f3,acc);
    acc = fmaf(dwv[4],f4,acc); acc = fmaf(dwv[5],f5,acc);
    const float delta = (acc > 20.f) ? acc : __logf(1.f + __expf(acc));
    const float du = delta*xv;
    float a0 = __expf(delta*A0), a1 = __expf(delta*A1);
    float a2 = __expf(delta*A2), a3 = __expf(delta*A3);
    float h0 = du*B0, h1 = du*B1, h2 = du*B2, h3 = du*B3;

    // intra-wave inclusive scan (width 64)
    #pragma unroll
    for (int s=1; s<64; s<<=1){
      float pa0=__shfl_up(a0,(unsigned)s,64), ph0=__shfl_up(h0,(unsigned)s,64);
      float pa1=__shfl_up(a1,(unsigned)s,64), ph1=__shfl_up(h1,(unsigned)s,64);
      float pa2=__shfl_up(a2,(unsigned)s,64), ph2=__shfl_up(h2,(unsigned)s,64);
      float pa3=__shfl_up(a3,(unsigned)s,64), ph3=__shfl_up(h3,(unsigned)s,64);
      if (lane >= s){
        h0 = fmaf(a0, ph0, h0); a0 *= pa0;
        h1 = fmaf(a1, ph1, h1); a1 *= pa1;
        h2 = fmaf(a2, ph2, h2); a2 *= pa2;
        h3 = fmaf(a3, ph3, h3); a3 *= pa3;
      }
    }

    const int buf = tt & 1;
    if (lane == 63){
      wc[buf][w][0]=a0; wc[buf][w][1]=a1; wc[buf][w][2]=a2; wc[buf][w][3]=a3;
      wc[buf][w][4]=h0; wc[buf][w][5]=h1; wc[buf][w][6]=h2; wc[buf][w][7]=h3;
    }
    __syncthreads();

    // exclusive wave-prefix W and tile total T (4 entries, broadcast reads)
    float WH0=0.f,WH1=0.f,WH2=0.f,WH3=0.f, WA0=1.f,WA1=1.f,WA2=1.f,WA3=1.f;
    float TH0=0.f,TH1=0.f,TH2=0.f,TH3=0.f, TA0=1.f,TA1=1.f,TA2=1.f,TA3=1.f;
    #pragma unroll
    for (int ww=0; ww<4; ww++){
      const float qa0=wc[buf][ww][0], qa1=wc[buf][ww][1], qa2=wc[buf][ww][2], qa3=wc[buf][ww][3];
      const float qh0=wc[buf][ww][4], qh1=wc[buf][ww][5], qh2=wc[buf][ww][6], qh3=wc[buf][ww][7];
      if (ww < w){
        WH0 = fmaf(qa0, WH0, qh0); WA0 *= qa0;
        WH1 = fmaf(qa1, WH1, qh1); WA1 *= qa1;
        WH2 = fmaf(qa2, WH2, qh2); WA2 *= qa2;
        WH3 = fmaf(qa3, WH3, qh3); WA3 *= qa3;
      }
      TH0 = fmaf(qa0, TH0, qh0); TA0 *= qa0;
      TH1 = fmaf(qa1, TH1, qh1); TA1 *= qa1;
      TH2 = fmaf(qa2, TH2, qh2); TA2 *= qa2;
      TH3 = fmaf(qa3, TH3, qh3); TA3 *= qa3;
    }

    // final h = a_incl * (WA*cH + WH) + h_incl ; y = D*x + C·h
    const float GH0 = fmaf(WA0, cH0, WH0);
    const float GH1 = fmaf(WA1, cH1, WH1);
    const float GH2 = fmaf(WA2, cH2, WH2);
    const float GH3 = fmaf(WA3, cH3, WH3);
    const float hf0 = fmaf(a0, GH0, h0);
    const float hf1 = fmaf(a1, GH1, h1);
    const float hf2 = fmaf(a2, GH2, h2);
    const float hf3 = fmaf(a3, GH3, h3);
    float yv = Dv*xv;
    yv = fmaf(C0,hf0,yv); yv = fmaf(C1,hf1,yv);
    yv = fmaf(C2,hf2,yv); yv = fmaf(C3,hf3,yv);
    yo[j] = yv;

    // update global carry: C' = combine(C, T)
    cH0 = fmaf(TA0, cH0, TH0);
    cH1 = fmaf(TA1, cH1, TH1);
    cH2 = fmaf(TA2, cH2, TH2);
    cH3 = fmaf(TA3, cH3, TH3);
  }
}

// ---------------- K6: merge + LayerNorm + SE scale -> yln[B,L,DI] ----------------
__global__ __launch_bounds__(256) void k_ln(
    const float* __restrict__ y0, const float* __restrict__ y1,
    const float* __restrict__ ln1g, const float* __restrict__ ln1b,
    const float* __restrict__ ln2g, const float* __restrict__ ln2b,
    const float* __restrict__ ex, float* __restrict__ yln)
{
  const int b  = blockIdx.y;
  const int j0 = blockIdx.x*64;
  __shared__ float v[DI][65];
  __shared__ float ps1[4][64], ps2[4][64];
  __shared__ float mu[64], rs[64];
  const int tid = threadIdx.x;
  const int jl = tid & 63, ds = tid >> 6;
  const float* p0 = y0 + (size_t)b*DI*LL + j0;
  const float* p1 = y1 + (size_t)b*DI*LL + j0;
  for (int it=0; it<48; it++){
    int d = ds*48 + it;
    v[d][jl] = p0[(size_t)d*LL + jl] + p1[(size_t)d*LL + jl];
  }
  __syncthreads();
  float s1=0.f, s2=0.f;
  for (int it=0; it<48; it++){
    float x = v[ds*48+it][jl];
    s1 += x; s2 += x*x;
  }
  ps1[ds][jl]=s1; ps2[ds][jl]=s2;
  __syncthreads();
  if (tid < 64){
    float t1 = ps1[0][tid]+ps1[1][tid]+ps1[2][tid]+ps1[3][tid];
    float t2 = ps2[0][tid]+ps2[1][tid]+ps2[2][tid]+ps2[3][tid];
    float m  = t1*(1.f/DI);
    float var= t2*(1.f/DI) - m*m;
    mu[tid]=m; rs[tid]=rsqrtf(var + 1e-5f);
  }
  __syncthreads();
  const int mod = (j0 >= HW) ? 1 : 0;
  const float* g  = mod? ln2g:ln1g;
  const float* bb = mod? ln2b:ln1b;
  const float* exm = ex + ((size_t)mod*B_ + b)*DI;
  for (int it=0; it<48; it++){
    int idx = it*256 + tid;
    int j = idx / DI;
    int d = idx - j*DI;
    float x = v[d][j];
    float o = (x - mu[j])*rs[j]*g[d] + bb[d];
    o *= exm[d];
    yln[((size_t)b*LL + j0 + j)*DI + d] = o;
  }
}

// ---------------- K7: output projection (LDS-W, register-blocked) ----------------
#define TMO 32
__global__ __launch_bounds__(128) void k_out(
    const float* __restrict__ yln, const float* __restrict__ Wo, float* __restrict__ out)
{
  __shared__ float lsW[DM*68];
  const int bid  = blockIdx.x;          // 0..255
  const int row0 = bid * TMO;           // global row = b*HW + hw
  const int b    = row0 >> 12;
  const int hw0  = row0 & (HW-1);
  const int tid  = threadIdx.x;
  const int cg = tid & 31, slot = tid >> 5;   // 4 slots
  const int r0 = slot * 8;                    // 8 rows per thread
  float acc[8][3];
  #pragma unroll
  for (int i=0;i<8;i++)
    #pragma unroll
    for (int q=0;q<3;q++) acc[i][q]=0.f;

  for (int c=0;c<6;c++){
    for (int t=tid; t<DM*64; t+=128){
      int dm = t>>6, kkl = t&63;
      lsW[dm*68 + kkl] = Wo[(size_t)dm*384 + c*64 + kkl];
    }
    __syncthreads();
    const float* xb = yln + ((size_t)b*LL + ((c<3)? hw0 : HW+hw0) + r0)*DI
                          + ((c<3)? c*64 : (c-3)*64);
    for (int kk4=0; kk4<16; kk4++){
      float4 xv[8];
      #pragma unroll
      for (int i=0;i<8;i++) xv[i] = *(const float4*)(xb + (size_t)i*DI + kk4*4);
      #pragma unroll
      for (int q=0;q<3;q++){
        const float4 wv = *(const float4*)(&lsW[(cg+32*q)*68 + kk4*4]);
        #pragma unroll
        for (int i=0;i<8;i++){
          acc[i][q] = fmaf(xv[i].x, wv.x, acc[i][q]);
          acc[i][q] = fmaf(xv[i].y, wv.y, acc[i][q]);
          acc[i][q] = fmaf(xv[i].z, wv.z, acc[i][q]);
          acc[i][q] = fmaf(xv[i].w, wv.w, acc[i][q]);
        }
      }
    }
    __syncthreads();
  }
  #pragma unroll
  for (int i=0;i<8;i++){
    float* ob = out + (size_t)(row0 + r0 + i)*DM;
    #pragma unroll
    for (int q=0;q<3;q++) ob[cg + 32*q] = acc[i][q];
  }
}

// ---------------- launch ----------------
extern "C" void kernel_launch(void* const* d_in, const int* in_sizes, int n_in,
                              void* d_out, int out_size, void* d_ws, size_t ws_size,
                              hipStream_t stream) {
  const float* x_rgb      = (const float*)d_in[0];
  const float* x_e        = (const float*)d_in[1];
  const float* in_proj_w  = (const float*)d_in[2];
  const float* in_proj_xw = (const float*)d_in[3];
  const float* conv_w     = (const float*)d_in[4];
  const float* conv_b     = (const float*)d_in[5];
  const float* conv_xw    = (const float*)d_in[6];
  const float* conv_xb    = (const float*)d_in[7];
  const float* xpw        = (const float*)d_in[8];
  const float* dtw        = (const float*)d_in[9];
  const float* dtb        = (const float*)d_in[10];
  const float* A_logs     = (const float*)d_in[11];
  const float* Ds         = (const float*)d_in[12];
  const float* ln1_g      = (const float*)d_in[13];
  const float* ln1_b      = (const float*)d_in[14];
  const float* ln2_g      = (const float*)d_in[15];
  const float* ln2_b      = (const float*)d_in[16];
  const float* out_proj_w = (const float*)d_in[17];
  const float* fc1_w1     = (const float*)d_in[18];
  const float* fc1_w2     = (const float*)d_in[19];
  const float* fc2_w1     = (const float*)d_in[20];
  const float* fc2_w2     = (const float*)d_in[21];

  float* ws = (float*)d_ws;
  // layout (floats):
  //  [0, 3145728)        xr_t/xe_t -> y0 (xr/xe dead after k_conv; scan overwrites with y0)
  //  [3145728, 6291456)  seq -> yln (alias; seq dead after k_scan)
  //  [6291456, 9437184)  y1
  //  [9437184, 9895936)  P (SoA planes, 4*14*8192)
  //  [9895936, ...)      sr, ex
  float* xr_t = ws;                        // 1,572,864
  float* xe_t = ws + 1572864;              // 1,572,864
  float* y0   = ws;                        // 3,145,728 (alias)
  float* seq  = ws + 3145728;              // 3,145,728
  float* yln  = seq;                       // alias
  float* y1   = ws + 6291456;              // 3,145,728
  float* P    = ws + 9437184;              //   458,752
  float* sr   = ws + 9895936;              //       768
  float* ex   = ws + 9896704;              //       768

  k_zero  <<<dim3(3), 256, 0, stream>>>(sr, 768);
  k_inproj<<<dim3(HW/64, B_, 2), 256, 0, stream>>>(x_rgb, x_e, in_proj_w, in_proj_xw, xr_t, xe_t, sr);
  k_conv  <<<dim3(HW/256, DI, B_*2), 256, 0, stream>>>(xr_t, xe_t, conv_w, conv_b, conv_xw, conv_xb, seq);
  k_se    <<<dim3(B_, 2), DI, 0, stream>>>(sr, fc1_w1, fc1_w2, fc2_w1, fc2_w2, ex);
  k_proj  <<<dim3(LL/256, KD, B_), 256, 0, stream>>>(seq, xpw, P);
  k_scan  <<<dim3(B_*KD*DI), 256, 0, stream>>>(seq, P, dtw, dtb, A_logs, Ds, y0, y1);
  k_ln    <<<dim3(LL/64, B_), 256, 0, stream>>>(y0, y1, ln1_g, ln1_b, ln2_g, ln2_b, ex, yln);
  k_out   <<<dim3(8192/TMO), 128, 0, stream>>>(yln, out_proj_w, (float*)d_out);
}

// Round 8
// 160.579 us; speedup vs baseline: 2.4048x; 1.2618x over previous
//
#include <hip/hip_runtime.h>
#include <math.h>

#define B_  2
#define H_  64
#define W_  64
#define HW  4096
#define DM  96
#define DI  192
#define NS  4
#define RK  6
#define KD  2
#define LL  8192   // 2*HW

__device__ __forceinline__ float sigmoidf_(float x){ return 1.f/(1.f+__expf(-x)); }
__device__ __forceinline__ float4 rev4(float4 v){ return make_float4(v.w,v.z,v.y,v.x); }

// ---------------- K0: zero the sr accumulator ----------------
__global__ void k_zero(float* __restrict__ p, int n){
  int i = blockIdx.x*256 + threadIdx.x;
  if (i < n) p[i] = 0.f;
}

// ---------------- K1: input projections -> channel-major [B,DI,HW] + fused channel sums ----------------
__global__ __launch_bounds__(256) void k_inproj(
    const float* __restrict__ xrgb, const float* __restrict__ xe,
    const float* __restrict__ wr,   const float* __restrict__ we,
    float* __restrict__ xrt, float* __restrict__ xet, float* __restrict__ sr)
{
  __shared__ float lsW[DI*100];
  __shared__ float lsum[DI];
  const int mod = blockIdx.z, b = blockIdx.y;
  const int hw0 = blockIdx.x * 64;
  const float* x  = mod ? xe  : xrgb;
  const float* Wp = mod ? we  : wr;
  float* out      = mod ? xet : xrt;
  const int tid = threadIdx.x;
  for (int t = tid; t < DI*DM; t += 256){
    int di = t / DM, kk = t - di*DM;
    lsW[di*100 + kk] = Wp[t];
  }
  if (tid < DI) lsum[tid] = 0.f;
  const int cg = tid & 31, slot = tid >> 5;   // 8 slots
  const int r0 = slot * 8;
  const float* xb = x + ((size_t)(b*HW) + hw0 + r0)*DM;
  float acc[8][6];
  #pragma unroll
  for (int i=0;i<8;i++)
    #pragma unroll
    for (int q=0;q<6;q++) acc[i][q]=0.f;
  __syncthreads();
  for (int kk4=0; kk4<DM/4; kk4++){
    float4 xv[8];
    #pragma unroll
    for (int i=0;i<8;i++) xv[i] = *(const float4*)(xb + (size_t)i*DM + kk4*4);
    #pragma unroll
    for (int q=0;q<6;q++){
      const float4 wv = *(const float4*)(&lsW[(cg+32*q)*100 + kk4*4]);
      #pragma unroll
      for (int i=0;i<8;i++){
        acc[i][q] = fmaf(xv[i].x, wv.x, acc[i][q]);
        acc[i][q] = fmaf(xv[i].y, wv.y, acc[i][q]);
        acc[i][q] = fmaf(xv[i].z, wv.z, acc[i][q]);
        acc[i][q] = fmaf(xv[i].w, wv.w, acc[i][q]);
      }
    }
  }
  #pragma unroll
  for (int q=0;q<6;q++){
    int di = cg + 32*q;
    float* ob = out + ((size_t)(b*DI + di))*HW + hw0 + r0;
    float ps = 0.f;
    #pragma unroll
    for (int i=0;i<8;i++){ ob[i] = acc[i][q]; ps += acc[i][q]; }
    atomicAdd(&lsum[di], ps);
  }
  __syncthreads();
  if (tid < DI) atomicAdd(&sr[((size_t)mod*B_ + b)*DI + tid], lsum[tid]);
}

// ---------------- K2: depthwise 3x3 conv + SiLU -> seq[B,DI,2HW] ----------------
__global__ __launch_bounds__(256) void k_conv(
    const float* __restrict__ xrt, const float* __restrict__ xet,
    const float* __restrict__ cwr, const float* __restrict__ cbr,
    const float* __restrict__ cwe, const float* __restrict__ cbe,
    float* __restrict__ seq)
{
  const int z = blockIdx.z; const int b = z >> 1, mod = z & 1;
  const int d = blockIdx.y;
  const float* in = (mod? xet:xrt) + ((size_t)b*DI + d)*HW;
  const float* wp = (mod? cwe:cwr) + d*9;
  const float  bias = (mod? cbe:cbr)[d];
  const int hw = blockIdx.x*256 + threadIdx.x;
  const int y = hw >> 6, x = hw & 63;
  float w[9];
  #pragma unroll
  for (int i=0;i<9;i++) w[i]=wp[i];
  float acc = bias;
  #pragma unroll
  for (int dy=-1;dy<=1;dy++){
    int yy = y+dy;
    if (yy<0||yy>=H_) continue;
    #pragma unroll
    for (int dx=-1;dx<=1;dx++){
      int xx = x+dx;
      if (xx<0||xx>=W_) continue;
      acc += in[yy*W_+xx]*w[(dy+1)*3 + dx+1];
    }
  }
  float v = acc * sigmoidf_(acc);
  seq[((size_t)b*DI + d)*LL + mod*HW + hw] = v;
}

// ---------------- K3: squeeze-excitation MLP (sr holds channel SUMS; scale by 1/HW) ----------------
__global__ void k_se(const float* __restrict__ sr,
                     const float* __restrict__ f11, const float* __restrict__ f12,
                     const float* __restrict__ f21, const float* __restrict__ f22,
                     float* __restrict__ ex)
{
  const int b = blockIdx.x, mod = blockIdx.y;
  const float* f1 = mod? f21:f11;
  const float* f2 = mod? f22:f12;
  __shared__ float s[DI];
  __shared__ float hid[12];
  const int t = threadIdx.x;
  s[t] = sr[((size_t)mod*B_ + b)*DI + t] * (1.f/HW);
  __syncthreads();
  if (t < 12){
    float a=0.f;
    for (int dd=0; dd<DI; dd++) a += f1[t*DI+dd]*s[dd];
    hid[t] = a * sigmoidf_(a);
  }
  __syncthreads();
  float a=0.f;
  #pragma unroll
  for (int h=0; h<12; h++) a += f2[t*12+h]*hid[h];
  ex[((size_t)mod*B_ + b)*DI + t] = sigmoidf_(a);
}

// ---------------- K4: x_proj of seq -> SoA planes P[bk][14][LL] ----------------
// planes 0..5 = dt-rank, 6..9 = B, 10..13 = C
__global__ __launch_bounds__(256) void k_proj(
    const float* __restrict__ seq, const float* __restrict__ xpw,
    float* __restrict__ P)
{
  __shared__ float lw[14*DI];
  const int b = blockIdx.z, k = blockIdx.y;
  const int j = blockIdx.x*256 + threadIdx.x;
  for (int t = threadIdx.x; t < 14*DI; t += 256) lw[t] = xpw[(size_t)k*14*DI + t];
  __syncthreads();
  float acc[14];
  #pragma unroll
  for (int c=0;c<14;c++) acc[c]=0.f;
  const float* sp = seq + (size_t)b*DI*LL + j;
  for (int dd=0; dd<DI; dd++){
    float s = sp[(size_t)dd*LL];
    #pragma unroll
    for (int cc=0; cc<14; cc++) acc[cc] = fmaf(lw[cc*DI+dd], s, acc[cc]);
  }
  const int bk = b*KD + k;
  float* Pb = P + (size_t)bk*14*LL;
  #pragma unroll
  for (int cc=0; cc<14; cc++) Pb[(size_t)cc*LL + j] = acc[cc];
}

// ---------------- K5: hybrid scan: 4 pos/thread serial + wave shfl-scan ----------------
#define GETC(v_, s_) ((s_)==0?(v_).x:((s_)==1?(v_).y:((s_)==2?(v_).z:(v_).w)))
#define NT8 8   // tiles of 1024

template<int KDIR>
__device__ __forceinline__ void scan_impl(
    const float* __restrict__ sq, const float* __restrict__ Pb,
    const float* A, const float* dwv, float bias, float Dv,
    float* __restrict__ yo, float (*wc)[4][8], int t)
{
  const int lane = t & 63, w = t >> 6;
  float cH[NS] = {0.f,0.f,0.f,0.f};

  for (int tt=0; tt<NT8; ++tt){
    const int j0 = KDIR ? (LL - 1024*tt - 4*t - 4) : (1024*tt + 4*t);
    float4 f0 = *(const float4*)(Pb + 0*(size_t)LL + j0);
    float4 f1 = *(const float4*)(Pb + 1*(size_t)LL + j0);
    float4 f2 = *(const float4*)(Pb + 2*(size_t)LL + j0);
    float4 f3 = *(const float4*)(Pb + 3*(size_t)LL + j0);
    float4 f4v= *(const float4*)(Pb + 4*(size_t)LL + j0);
    float4 f5 = *(const float4*)(Pb + 5*(size_t)LL + j0);
    float4 fx = *(const float4*)(sq + j0);
    float4 b0 = *(const float4*)(Pb + 6*(size_t)LL + j0);
    float4 b1 = *(const float4*)(Pb + 7*(size_t)LL + j0);
    float4 b2 = *(const float4*)(Pb + 8*(size_t)LL + j0);
    float4 b3 = *(const float4*)(Pb + 9*(size_t)LL + j0);
    float4 c0 = *(const float4*)(Pb + 10*(size_t)LL + j0);
    float4 c1 = *(const float4*)(Pb + 11*(size_t)LL + j0);
    float4 c2 = *(const float4*)(Pb + 12*(size_t)LL + j0);
    float4 c3 = *(const float4*)(Pb + 13*(size_t)LL + j0);
    if (KDIR){
      f0=rev4(f0); f1=rev4(f1); f2=rev4(f2); f3=rev4(f3); f4v=rev4(f4v); f5=rev4(f5);
      fx=rev4(fx);
      b0=rev4(b0); b1=rev4(b1); b2=rev4(b2); b3=rev4(b3);
      c0=rev4(c0); c1=rev4(c1); c2=rev4(c2); c3=rev4(c3);
    }

    // per-position delta, du (l-order components)
    float del[4], du[4];
    #pragma unroll
    for (int i=0;i<4;i++){
      float acc = bias;
      acc = fmaf(dwv[0],GETC(f0,i),acc); acc = fmaf(dwv[1],GETC(f1,i),acc);
      acc = fmaf(dwv[2],GETC(f2,i),acc); acc = fmaf(dwv[3],GETC(f3,i),acc);
      acc = fmaf(dwv[4],GETC(f4v,i),acc); acc = fmaf(dwv[5],GETC(f5,i),acc);
      del[i] = (acc > 20.f) ? acc : __logf(1.f + __expf(acc));
      du[i]  = del[i]*GETC(fx,i);
    }

    // thread-local serial scan, keep per-position inclusive values
    float lA[NS][4], lH[NS][4];
    #pragma unroll
    for (int n=0;n<NS;n++){
      float rA=1.f, rH=0.f;
      #pragma unroll
      for (int i=0;i<4;i++){
        float Bi = GETC((n==0?b0:n==1?b1:n==2?b2:b3), i);
        float ai = __expf(del[i]*A[n]);
        rH = fmaf(ai, rH, du[i]*Bi);
        rA *= ai;
        lA[n][i]=rA; lH[n][i]=rH;
      }
    }

    // wave inclusive scan over thread carries
    float sA[NS], sH[NS];
    #pragma unroll
    for (int n=0;n<NS;n++){ sA[n]=lA[n][3]; sH[n]=lH[n][3]; }
    #pragma unroll
    for (int s=1; s<64; s<<=1){
      float pa[NS], ph[NS];
      #pragma unroll
      for (int n=0;n<NS;n++){ pa[n]=__shfl_up(sA[n],(unsigned)s,64); ph[n]=__shfl_up(sH[n],(unsigned)s,64); }
      if (lane >= s){
        #pragma unroll
        for (int n=0;n<NS;n++){ sH[n]=fmaf(sA[n],ph[n],sH[n]); sA[n]*=pa[n]; }
      }
    }
    // lane-exclusive prefix
    float eA[NS], eH[NS];
    #pragma unroll
    for (int n=0;n<NS;n++){
      float xa = __shfl_up(sA[n],1u,64), xh = __shfl_up(sH[n],1u,64);
      eA[n] = lane ? xa : 1.f;
      eH[n] = lane ? xh : 0.f;
    }

    const int buf = tt & 1;
    if (lane == 63){
      #pragma unroll
      for (int n=0;n<NS;n++){ wc[buf][w][n]=sA[n]; wc[buf][w][4+n]=sH[n]; }
    }
    __syncthreads();

    // wave-exclusive prefix W and tile total T
    float WA[NS]={1.f,1.f,1.f,1.f}, WH[NS]={0.f,0.f,0.f,0.f};
    float TA[NS]={1.f,1.f,1.f,1.f}, TH[NS]={0.f,0.f,0.f,0.f};
    #pragma unroll
    for (int ww=0; ww<4; ww++){
      #pragma unroll
      for (int n=0;n<NS;n++){
        float qa = wc[buf][ww][n], qh = wc[buf][ww][4+n];
        if (ww < w){ WH[n]=fmaf(qa,WH[n],qh); WA[n]*=qa; }
        TH[n]=fmaf(qa,TH[n],qh); TA[n]*=qa;
      }
    }

    // per-thread prefix state (h only needed)
    float PH[NS];
    #pragma unroll
    for (int n=0;n<NS;n++){
      float GH = fmaf(WA[n], cH[n], WH[n]);     // prefix after global carry + prior waves
      PH[n] = fmaf(eA[n], GH, eH[n]);           // + prior lanes
    }

    // apply & emit y
    float yv[4];
    #pragma unroll
    for (int i=0;i<4;i++){
      float y = Dv*GETC(fx,i);
      #pragma unroll
      for (int n=0;n<NS;n++){
        float h = fmaf(lA[n][i], PH[n], lH[n][i]);
        float Ci = GETC((n==0?c0:n==1?c1:n==2?c2:c3), i);
        y = fmaf(Ci, h, y);
      }
      yv[i] = y;
    }
    float4 o = make_float4(yv[0],yv[1],yv[2],yv[3]);
    if (KDIR) o = rev4(o);
    *(float4*)(yo + j0) = o;

    // advance global carry
    #pragma unroll
    for (int n=0;n<NS;n++) cH[n] = fmaf(TA[n], cH[n], TH[n]);
  }
}

__global__ __launch_bounds__(256, 3) void k_scan(
    const float* __restrict__ seq,  const float* __restrict__ P,
    const float* __restrict__ dtw,  const float* __restrict__ dtb,
    const float* __restrict__ Alogs,const float* __restrict__ Dsp,
    float* __restrict__ y0, float* __restrict__ y1)
{
  const int gid = blockIdx.x;
  const int d = gid % DI;
  const int k = (gid / DI) % KD;
  const int b = gid / (DI*KD);
  const int t = threadIdx.x;
  const int kd = k*DI + d;
  float A[NS];
  #pragma unroll
  for (int n=0;n<NS;n++) A[n] = -__expf(Alogs[kd*NS+n]);
  float dwv[RK];
  #pragma unroll
  for (int r=0;r<RK;r++) dwv[r] = dtw[kd*RK+r];
  const float bias = dtb[kd];
  const float Dv   = Dsp[kd];
  const float* sq = seq + ((size_t)b*DI + d)*LL;
  const int bk = b*KD + k;
  const float* Pb = P + (size_t)bk*14*LL;
  float* yo = (k ? y1 : y0) + ((size_t)b*DI + d)*LL;

  __shared__ float wc[2][4][8];

  if (k == 0) scan_impl<0>(sq, Pb, A, dwv, bias, Dv, yo, wc, t);
  else        scan_impl<1>(sq, Pb, A, dwv, bias, Dv, yo, wc, t);
}

// ---------------- K6: merge + LayerNorm + SE scale -> yln[B,L,DI] ----------------
__global__ __launch_bounds__(256) void k_ln(
    const float* __restrict__ y0, const float* __restrict__ y1,
    const float* __restrict__ ln1g, const float* __restrict__ ln1b,
    const float* __restrict__ ln2g, const float* __restrict__ ln2b,
    const float* __restrict__ ex, float* __restrict__ yln)
{
  const int b  = blockIdx.y;
  const int j0 = blockIdx.x*64;
  __shared__ float v[DI][65];
  __shared__ float ps1[4][64], ps2[4][64];
  __shared__ float mu[64], rs[64];
  const int tid = threadIdx.x;
  const int jl = tid & 63, ds = tid >> 6;
  const float* p0 = y0 + (size_t)b*DI*LL + j0;
  const float* p1 = y1 + (size_t)b*DI*LL + j0;
  for (int it=0; it<48; it++){
    int d = ds*48 + it;
    v[d][jl] = p0[(size_t)d*LL + jl] + p1[(size_t)d*LL + jl];
  }
  __syncthreads();
  float s1=0.f, s2=0.f;
  for (int it=0; it<48; it++){
    float x = v[ds*48+it][jl];
    s1 += x; s2 += x*x;
  }
  ps1[ds][jl]=s1; ps2[ds][jl]=s2;
  __syncthreads();
  if (tid < 64){
    float t1 = ps1[0][tid]+ps1[1][tid]+ps1[2][tid]+ps1[3][tid];
    float t2 = ps2[0][tid]+ps2[1][tid]+ps2[2][tid]+ps2[3][tid];
    float m  = t1*(1.f/DI);
    float var= t2*(1.f/DI) - m*m;
    mu[tid]=m; rs[tid]=rsqrtf(var + 1e-5f);
  }
  __syncthreads();
  const int mod = (j0 >= HW) ? 1 : 0;
  const float* g  = mod? ln2g:ln1g;
  const float* bb = mod? ln2b:ln1b;
  const float* exm = ex + ((size_t)mod*B_ + b)*DI;
  for (int it=0; it<48; it++){
    int idx = it*256 + tid;
    int j = idx / DI;
    int d = idx - j*DI;
    float x = v[d][j];
    float o = (x - mu[j])*rs[j]*g[d] + bb[d];
    o *= exm[d];
    yln[((size_t)b*LL + j0 + j)*DI + d] = o;
  }
}

// ---------------- K7: output projection (LDS-W, register-blocked) ----------------
#define TMO 32
__global__ __launch_bounds__(128) void k_out(
    const float* __restrict__ yln, const float* __restrict__ Wo, float* __restrict__ out)
{
  __shared__ float lsW[DM*68];
  const int bid  = blockIdx.x;          // 0..255
  const int row0 = bid * TMO;           // global row = b*HW + hw
  const int b    = row0 >> 12;
  const int hw0  = row0 & (HW-1);
  const int tid  = threadIdx.x;
  const int cg = tid & 31, slot = tid >> 5;   // 4 slots
  const int r0 = slot * 8;                    // 8 rows per thread
  float acc[8][3];
  #pragma unroll
  for (int i=0;i<8;i++)
    #pragma unroll
    for (int q=0;q<3;q++) acc[i][q]=0.f;

  for (int c=0;c<6;c++){
    for (int t=tid; t<DM*64; t+=128){
      int dm = t>>6, kkl = t&63;
      lsW[dm*68 + kkl] = Wo[(size_t)dm*384 + c*64 + kkl];
    }
    __syncthreads();
    const float* xb = yln + ((size_t)b*LL + ((c<3)? hw0 : HW+hw0) + r0)*DI
                          + ((c<3)? c*64 : (c-3)*64);
    for (int kk4=0; kk4<16; kk4++){
      float4 xv[8];
      #pragma unroll
      for (int i=0;i<8;i++) xv[i] = *(const float4*)(xb + (size_t)i*DI + kk4*4);
      #pragma unroll
      for (int q=0;q<3;q++){
        const float4 wv = *(const float4*)(&lsW[(cg+32*q)*68 + kk4*4]);
        #pragma unroll
        for (int i=0;i<8;i++){
          acc[i][q] = fmaf(xv[i].x, wv.x, acc[i][q]);
          acc[i][q] = fmaf(xv[i].y, wv.y, acc[i][q]);
          acc[i][q] = fmaf(xv[i].z, wv.z, acc[i][q]);
          acc[i][q] = fmaf(xv[i].w, wv.w, acc[i][q]);
        }
      }
    }
    __syncthreads();
  }
  #pragma unroll
  for (int i=0;i<8;i++){
    float* ob = out + (size_t)(row0 + r0 + i)*DM;
    #pragma unroll
    for (int q=0;q<3;q++) ob[cg + 32*q] = acc[i][q];
  }
}

// ---------------- launch ----------------
extern "C" void kernel_launch(void* const* d_in, const int* in_sizes, int n_in,
                              void* d_out, int out_size, void* d_ws, size_t ws_size,
                              hipStream_t stream) {
  const float* x_rgb      = (const float*)d_in[0];
  const float* x_e        = (const float*)d_in[1];
  const float* in_proj_w  = (const float*)d_in[2];
  const float* in_proj_xw = (const float*)d_in[3];
  const float* conv_w     = (const float*)d_in[4];
  const float* conv_b     = (const float*)d_in[5];
  const float* conv_xw    = (const float*)d_in[6];
  const float* conv_xb    = (const float*)d_in[7];
  const float* xpw        = (const float*)d_in[8];
  const float* dtw        = (const float*)d_in[9];
  const float* dtb        = (const float*)d_in[10];
  const float* A_logs     = (const float*)d_in[11];
  const float* Ds         = (const float*)d_in[12];
  const float* ln1_g      = (const float*)d_in[13];
  const float* ln1_b      = (const float*)d_in[14];
  const float* ln2_g      = (const float*)d_in[15];
  const float* ln2_b      = (const float*)d_in[16];
  const float* out_proj_w = (const float*)d_in[17];
  const float* fc1_w1     = (const float*)d_in[18];
  const float* fc1_w2     = (const float*)d_in[19];
  const float* fc2_w1     = (const float*)d_in[20];
  const float* fc2_w2     = (const float*)d_in[21];

  float* ws = (float*)d_ws;
  // layout (floats):
  //  [0, 3145728)        xr_t/xe_t -> y0 (xr/xe dead after k_conv; scan overwrites with y0)
  //  [3145728, 6291456)  seq -> yln (alias; seq dead after k_scan)
  //  [6291456, 9437184)  y1
  //  [9437184, 9895936)  P (SoA planes, 4*14*8192)
  //  [9895936, ...)      sr, ex
  float* xr_t = ws;                        // 1,572,864
  float* xe_t = ws + 1572864;              // 1,572,864
  float* y0   = ws;                        // 3,145,728 (alias)
  float* seq  = ws + 3145728;              // 3,145,728
  float* yln  = seq;                       // alias
  float* y1   = ws + 6291456;              // 3,145,728
  float* P    = ws + 9437184;              //   458,752
  float* sr   = ws + 9895936;              //       768
  float* ex   = ws + 9896704;              //       768

  k_zero  <<<dim3(3), 256, 0, stream>>>(sr, 768);
  k_inproj<<<dim3(HW/64, B_, 2), 256, 0, stream>>>(x_rgb, x_e, in_proj_w, in_proj_xw, xr_t, xe_t, sr);
  k_conv  <<<dim3(HW/256, DI, B_*2), 256, 0, stream>>>(xr_t, xe_t, conv_w, conv_b, conv_xw, conv_xb, seq);
  k_se    <<<dim3(B_, 2), DI, 0, stream>>>(sr, fc1_w1, fc1_w2, fc2_w1, fc2_w2, ex);
  k_proj  <<<dim3(LL/256, KD, B_), 256, 0, stream>>>(seq, xpw, P);
  k_scan  <<<dim3(B_*KD*DI), 256, 0, stream>>>(seq, P, dtw, dtb, A_logs, Ds, y0, y1);
  k_ln    <<<dim3(LL/64, B_), 256, 0, stream>>>(y0, y1, ln1_g, ln1_b, ln2_g, ln2_b, ex, yln);
  k_out   <<<dim3(8192/TMO), 128, 0, stream>>>(yln, out_proj_w, (float*)d_out);
}

// Round 9
// 139.485 us; speedup vs baseline: 2.7685x; 1.1512x over previous
//
#include <hip/hip_runtime.h>
#include <math.h>

#define B_  2
#define H_  64
#define W_  64
#define HW  4096
#define DM  96
#define DI  192
#define NS  4
#define RK  6
#define KD  2
#define LL  8192   // 2*HW

__device__ __forceinline__ float sigmoidf_(float x){ return 1.f/(1.f+__expf(-x)); }
__device__ __forceinline__ float4 rev4(float4 v){ return make_float4(v.w,v.z,v.y,v.x); }

// ---------------- K0: zero an accumulator buffer ----------------
__global__ void k_zero(float* __restrict__ p, int n){
  int i = blockIdx.x*256 + threadIdx.x;
  if (i < n) p[i] = 0.f;
}

// ---------------- K1: input projections -> channel-major [B,DI,HW] + fused channel sums ----------------
__global__ __launch_bounds__(256) void k_inproj(
    const float* __restrict__ xrgb, const float* __restrict__ xe,
    const float* __restrict__ wr,   const float* __restrict__ we,
    float* __restrict__ xrt, float* __restrict__ xet, float* __restrict__ sr)
{
  __shared__ float lsW[DI*100];
  __shared__ float lsum[DI];
  const int mod = blockIdx.z, b = blockIdx.y;
  const int hw0 = blockIdx.x * 64;
  const float* x  = mod ? xe  : xrgb;
  const float* Wp = mod ? we  : wr;
  float* out      = mod ? xet : xrt;
  const int tid = threadIdx.x;
  for (int t = tid; t < DI*DM; t += 256){
    int di = t / DM, kk = t - di*DM;
    lsW[di*100 + kk] = Wp[t];
  }
  if (tid < DI) lsum[tid] = 0.f;
  const int cg = tid & 31, slot = tid >> 5;   // 8 slots
  const int r0 = slot * 8;
  const float* xb = x + ((size_t)(b*HW) + hw0 + r0)*DM;
  float acc[8][6];
  #pragma unroll
  for (int i=0;i<8;i++)
    #pragma unroll
    for (int q=0;q<6;q++) acc[i][q]=0.f;
  __syncthreads();
  for (int kk4=0; kk4<DM/4; kk4++){
    float4 xv[8];
    #pragma unroll
    for (int i=0;i<8;i++) xv[i] = *(const float4*)(xb + (size_t)i*DM + kk4*4);
    #pragma unroll
    for (int q=0;q<6;q++){
      const float4 wv = *(const float4*)(&lsW[(cg+32*q)*100 + kk4*4]);
      #pragma unroll
      for (int i=0;i<8;i++){
        acc[i][q] = fmaf(xv[i].x, wv.x, acc[i][q]);
        acc[i][q] = fmaf(xv[i].y, wv.y, acc[i][q]);
        acc[i][q] = fmaf(xv[i].z, wv.z, acc[i][q]);
        acc[i][q] = fmaf(xv[i].w, wv.w, acc[i][q]);
      }
    }
  }
  #pragma unroll
  for (int q=0;q<6;q++){
    int di = cg + 32*q;
    float* ob = out + ((size_t)(b*DI + di))*HW + hw0 + r0;
    float ps = 0.f;
    #pragma unroll
    for (int i=0;i<8;i++){ ob[i] = acc[i][q]; ps += acc[i][q]; }
    atomicAdd(&lsum[di], ps);
  }
  __syncthreads();
  if (tid < DI) atomicAdd(&sr[((size_t)mod*B_ + b)*DI + tid], lsum[tid]);
}

// ---------------- K2: depthwise 3x3 conv + SiLU -> seq[B,DI,2HW] ----------------
__global__ __launch_bounds__(256) void k_conv(
    const float* __restrict__ xrt, const float* __restrict__ xet,
    const float* __restrict__ cwr, const float* __restrict__ cbr,
    const float* __restrict__ cwe, const float* __restrict__ cbe,
    float* __restrict__ seq)
{
  const int z = blockIdx.z; const int b = z >> 1, mod = z & 1;
  const int d = blockIdx.y;
  const float* in = (mod? xet:xrt) + ((size_t)b*DI + d)*HW;
  const float* wp = (mod? cwe:cwr) + d*9;
  const float  bias = (mod? cbe:cbr)[d];
  const int hw = blockIdx.x*256 + threadIdx.x;
  const int y = hw >> 6, x = hw & 63;
  float w[9];
  #pragma unroll
  for (int i=0;i<9;i++) w[i]=wp[i];
  float acc = bias;
  #pragma unroll
  for (int dy=-1;dy<=1;dy++){
    int yy = y+dy;
    if (yy<0||yy>=H_) continue;
    #pragma unroll
    for (int dx=-1;dx<=1;dx++){
      int xx = x+dx;
      if (xx<0||xx>=W_) continue;
      acc += in[yy*W_+xx]*w[(dy+1)*3 + dx+1];
    }
  }
  float v = acc * sigmoidf_(acc);
  seq[((size_t)b*DI + d)*LL + mod*HW + hw] = v;
}

// ---------------- K3: squeeze-excitation MLP (sr holds channel SUMS; scale by 1/HW) ----------------
__global__ void k_se(const float* __restrict__ sr,
                     const float* __restrict__ f11, const float* __restrict__ f12,
                     const float* __restrict__ f21, const float* __restrict__ f22,
                     float* __restrict__ ex)
{
  const int b = blockIdx.x, mod = blockIdx.y;
  const float* f1 = mod? f21:f11;
  const float* f2 = mod? f22:f12;
  __shared__ float s[DI];
  __shared__ float hid[12];
  const int t = threadIdx.x;
  s[t] = sr[((size_t)mod*B_ + b)*DI + t] * (1.f/HW);
  __syncthreads();
  if (t < 12){
    float a=0.f;
    for (int dd=0; dd<DI; dd++) a += f1[t*DI+dd]*s[dd];
    hid[t] = a * sigmoidf_(a);
  }
  __syncthreads();
  float a=0.f;
  #pragma unroll
  for (int h=0; h<12; h++) a += f2[t*12+h]*hid[h];
  ex[((size_t)mod*B_ + b)*DI + t] = sigmoidf_(a);
}

// ---------------- K4: x_proj of seq -> SoA planes P[bk][14][LL], dd-split x4 ----------------
// planes 0..5 = dt-rank, 6..9 = B, 10..13 = C
__global__ __launch_bounds__(256) void k_proj(
    const float* __restrict__ seq, const float* __restrict__ xpw,
    float* __restrict__ P)
{
  __shared__ float lw[14*DI];
  __shared__ float part[3][14][66];
  const int b = blockIdx.z, k = blockIdx.y;
  const int j0 = blockIdx.x*64;
  const int tid = threadIdx.x;
  const int jl = tid & 63, dq = tid >> 6;   // dq: 0..3, 48 channels each
  const int j = j0 + jl;
  for (int t = tid; t < 14*DI; t += 256) lw[t] = xpw[(size_t)k*14*DI + t];
  __syncthreads();
  float acc[14];
  #pragma unroll
  for (int c=0;c<14;c++) acc[c]=0.f;
  const float* sp = seq + (size_t)b*DI*LL + (size_t)(dq*48)*LL + j;
  const float* lwq = lw + dq*48;
  for (int dd=0; dd<48; dd++){
    float s = sp[(size_t)dd*LL];
    #pragma unroll
    for (int cc=0; cc<14; cc++) acc[cc] = fmaf(lwq[cc*DI+dd], s, acc[cc]);
  }
  if (dq){
    #pragma unroll
    for (int cc=0; cc<14; cc++) part[dq-1][cc][jl] = acc[cc];
  }
  __syncthreads();
  if (dq == 0){
    const int bk = b*KD + k;
    float* Pb = P + (size_t)bk*14*LL;
    #pragma unroll
    for (int cc=0; cc<14; cc++){
      float v = acc[cc] + part[0][cc][jl] + part[1][cc][jl] + part[2][cc][jl];
      Pb[(size_t)cc*LL + j] = v;
    }
  }
}

// ---------------- K5: hybrid scan: 4 pos/thread serial + wave shfl-scan ----------------
#define GETC(v_, s_) ((s_)==0?(v_).x:((s_)==1?(v_).y:((s_)==2?(v_).z:(v_).w)))
#define NT8 8   // tiles of 1024

template<int KDIR>
__device__ __forceinline__ void scan_impl(
    const float* __restrict__ sq, const float* __restrict__ Pb,
    const float* A, const float* dwv, float bias, float Dv,
    float* __restrict__ yo, float (*wc)[4][8], int t)
{
  const int lane = t & 63, w = t >> 6;
  float cH[NS] = {0.f,0.f,0.f,0.f};

  for (int tt=0; tt<NT8; ++tt){
    const int j0 = KDIR ? (LL - 1024*tt - 4*t - 4) : (1024*tt + 4*t);
    float4 f0 = *(const float4*)(Pb + 0*(size_t)LL + j0);
    float4 f1 = *(const float4*)(Pb + 1*(size_t)LL + j0);
    float4 f2 = *(const float4*)(Pb + 2*(size_t)LL + j0);
    float4 f3 = *(const float4*)(Pb + 3*(size_t)LL + j0);
    float4 f4v= *(const float4*)(Pb + 4*(size_t)LL + j0);
    float4 f5 = *(const float4*)(Pb + 5*(size_t)LL + j0);
    float4 fx = *(const float4*)(sq + j0);
    float4 b0 = *(const float4*)(Pb + 6*(size_t)LL + j0);
    float4 b1 = *(const float4*)(Pb + 7*(size_t)LL + j0);
    float4 b2 = *(const float4*)(Pb + 8*(size_t)LL + j0);
    float4 b3 = *(const float4*)(Pb + 9*(size_t)LL + j0);
    float4 c0 = *(const float4*)(Pb + 10*(size_t)LL + j0);
    float4 c1 = *(const float4*)(Pb + 11*(size_t)LL + j0);
    float4 c2 = *(const float4*)(Pb + 12*(size_t)LL + j0);
    float4 c3 = *(const float4*)(Pb + 13*(size_t)LL + j0);
    if (KDIR){
      f0=rev4(f0); f1=rev4(f1); f2=rev4(f2); f3=rev4(f3); f4v=rev4(f4v); f5=rev4(f5);
      fx=rev4(fx);
      b0=rev4(b0); b1=rev4(b1); b2=rev4(b2); b3=rev4(b3);
      c0=rev4(c0); c1=rev4(c1); c2=rev4(c2); c3=rev4(c3);
    }

    float del[4], du[4];
    #pragma unroll
    for (int i=0;i<4;i++){
      float acc = bias;
      acc = fmaf(dwv[0],GETC(f0,i),acc); acc = fmaf(dwv[1],GETC(f1,i),acc);
      acc = fmaf(dwv[2],GETC(f2,i),acc); acc = fmaf(dwv[3],GETC(f3,i),acc);
      acc = fmaf(dwv[4],GETC(f4v,i),acc); acc = fmaf(dwv[5],GETC(f5,i),acc);
      del[i] = (acc > 20.f) ? acc : __logf(1.f + __expf(acc));
      du[i]  = del[i]*GETC(fx,i);
    }

    float lA[NS][4], lH[NS][4];
    #pragma unroll
    for (int n=0;n<NS;n++){
      float rA=1.f, rH=0.f;
      #pragma unroll
      for (int i=0;i<4;i++){
        float Bi = GETC((n==0?b0:n==1?b1:n==2?b2:b3), i);
        float ai = __expf(del[i]*A[n]);
        rH = fmaf(ai, rH, du[i]*Bi);
        rA *= ai;
        lA[n][i]=rA; lH[n][i]=rH;
      }
    }

    float sA[NS], sH[NS];
    #pragma unroll
    for (int n=0;n<NS;n++){ sA[n]=lA[n][3]; sH[n]=lH[n][3]; }
    #pragma unroll
    for (int s=1; s<64; s<<=1){
      float pa[NS], ph[NS];
      #pragma unroll
      for (int n=0;n<NS;n++){ pa[n]=__shfl_up(sA[n],(unsigned)s,64); ph[n]=__shfl_up(sH[n],(unsigned)s,64); }
      if (lane >= s){
        #pragma unroll
        for (int n=0;n<NS;n++){ sH[n]=fmaf(sA[n],ph[n],sH[n]); sA[n]*=pa[n]; }
      }
    }
    float eA[NS], eH[NS];
    #pragma unroll
    for (int n=0;n<NS;n++){
      float xa = __shfl_up(sA[n],1u,64), xh = __shfl_up(sH[n],1u,64);
      eA[n] = lane ? xa : 1.f;
      eH[n] = lane ? xh : 0.f;
    }

    const int buf = tt & 1;
    if (lane == 63){
      #pragma unroll
      for (int n=0;n<NS;n++){ wc[buf][w][n]=sA[n]; wc[buf][w][4+n]=sH[n]; }
    }
    __syncthreads();

    float WA[NS]={1.f,1.f,1.f,1.f}, WH[NS]={0.f,0.f,0.f,0.f};
    float TA[NS]={1.f,1.f,1.f,1.f}, TH[NS]={0.f,0.f,0.f,0.f};
    #pragma unroll
    for (int ww=0; ww<4; ww++){
      #pragma unroll
      for (int n=0;n<NS;n++){
        float qa = wc[buf][ww][n], qh = wc[buf][ww][4+n];
        if (ww < w){ WH[n]=fmaf(qa,WH[n],qh); WA[n]*=qa; }
        TH[n]=fmaf(qa,TH[n],qh); TA[n]*=qa;
      }
    }

    float PH[NS];
    #pragma unroll
    for (int n=0;n<NS;n++){
      float GH = fmaf(WA[n], cH[n], WH[n]);
      PH[n] = fmaf(eA[n], GH, eH[n]);
    }

    float yv[4];
    #pragma unroll
    for (int i=0;i<4;i++){
      float y = Dv*GETC(fx,i);
      #pragma unroll
      for (int n=0;n<NS;n++){
        float h = fmaf(lA[n][i], PH[n], lH[n][i]);
        float Ci = GETC((n==0?c0:n==1?c1:n==2?c2:c3), i);
        y = fmaf(Ci, h, y);
      }
      yv[i] = y;
    }
    float4 o = make_float4(yv[0],yv[1],yv[2],yv[3]);
    if (KDIR) o = rev4(o);
    *(float4*)(yo + j0) = o;

    #pragma unroll
    for (int n=0;n<NS;n++) cH[n] = fmaf(TA[n], cH[n], TH[n]);
  }
}

__global__ __launch_bounds__(256, 3) void k_scan(
    const float* __restrict__ seq,  const float* __restrict__ P,
    const float* __restrict__ dtw,  const float* __restrict__ dtb,
    const float* __restrict__ Alogs,const float* __restrict__ Dsp,
    float* __restrict__ y0, float* __restrict__ y1)
{
  const int gid = blockIdx.x;
  const int d = gid % DI;
  const int k = (gid / DI) % KD;
  const int b = gid / (DI*KD);
  const int t = threadIdx.x;
  const int kd = k*DI + d;
  float A[NS];
  #pragma unroll
  for (int n=0;n<NS;n++) A[n] = -__expf(Alogs[kd*NS+n]);
  float dwv[RK];
  #pragma unroll
  for (int r=0;r<RK;r++) dwv[r] = dtw[kd*RK+r];
  const float bias = dtb[kd];
  const float Dv   = Dsp[kd];
  const float* sq = seq + ((size_t)b*DI + d)*LL;
  const int bk = b*KD + k;
  const float* Pb = P + (size_t)bk*14*LL;
  float* yo = (k ? y1 : y0) + ((size_t)b*DI + d)*LL;

  __shared__ float wc[2][4][8];

  if (k == 0) scan_impl<0>(sq, Pb, A, dwv, bias, Dv, yo, wc, t);
  else        scan_impl<1>(sq, Pb, A, dwv, bias, Dv, yo, wc, t);
}

// ---------------- K6: merge + LayerNorm + SE scale -> yln[B,L,DI] ----------------
__global__ __launch_bounds__(256) void k_ln(
    const float* __restrict__ y0, const float* __restrict__ y1,
    const float* __restrict__ ln1g, const float* __restrict__ ln1b,
    const float* __restrict__ ln2g, const float* __restrict__ ln2b,
    const float* __restrict__ ex, float* __restrict__ yln)
{
  const int b  = blockIdx.y;
  const int j0 = blockIdx.x*64;
  __shared__ float v[DI][65];
  __shared__ float ps1[4][64], ps2[4][64];
  __shared__ float mu[64], rs[64];
  const int tid = threadIdx.x;
  const int jl = tid & 63, ds = tid >> 6;
  const float* p0 = y0 + (size_t)b*DI*LL + j0;
  const float* p1 = y1 + (size_t)b*DI*LL + j0;
  for (int it=0; it<48; it++){
    int d = ds*48 + it;
    v[d][jl] = p0[(size_t)d*LL + jl] + p1[(size_t)d*LL + jl];
  }
  __syncthreads();
  float s1=0.f, s2=0.f;
  for (int it=0; it<48; it++){
    float x = v[ds*48+it][jl];
    s1 += x; s2 += x*x;
  }
  ps1[ds][jl]=s1; ps2[ds][jl]=s2;
  __syncthreads();
  if (tid < 64){
    float t1 = ps1[0][tid]+ps1[1][tid]+ps1[2][tid]+ps1[3][tid];
    float t2 = ps2[0][tid]+ps2[1][tid]+ps2[2][tid]+ps2[3][tid];
    float m  = t1*(1.f/DI);
    float var= t2*(1.f/DI) - m*m;
    mu[tid]=m; rs[tid]=rsqrtf(var + 1e-5f);
  }
  __syncthreads();
  const int mod = (j0 >= HW) ? 1 : 0;
  const float* g  = mod? ln2g:ln1g;
  const float* bb = mod? ln2b:ln1b;
  const float* exm = ex + ((size_t)mod*B_ + b)*DI;
  for (int it=0; it<48; it++){
    int idx = it*256 + tid;
    int j = idx / DI;
    int d = idx - j*DI;
    float x = v[d][j];
    float o = (x - mu[j])*rs[j]*g[d] + bb[d];
    o *= exm[d];
    yln[((size_t)b*LL + j0 + j)*DI + d] = o;
  }
}

// ---------------- K7: output projection, k-split x2 + atomicAdd ----------------
__global__ __launch_bounds__(128) void k_out(
    const float* __restrict__ yln, const float* __restrict__ Wo, float* __restrict__ out)
{
  __shared__ float lsW[DM*68];
  const int bid  = blockIdx.x;          // 0..511
  const int ks   = bid & 1;             // modality half of the 384-k reduction
  const int rg   = bid >> 1;            // 0..255 row group
  const int row0 = rg * 32;
  const int b    = row0 >> 12;
  const int hw0  = row0 & (HW-1);
  const int tid  = threadIdx.x;
  const int cg = tid & 31, slot = tid >> 5;   // 4 slots
  const int r0 = slot * 8;                    // 8 rows per thread
  float acc[8][3];
  #pragma unroll
  for (int i=0;i<8;i++)
    #pragma unroll
    for (int q=0;q<3;q++) acc[i][q]=0.f;

  const float* xrow = yln + ((size_t)b*LL + (ks ? HW+hw0 : hw0) + r0)*DI;
  for (int c=0;c<3;c++){
    const int colbase = ks*192 + c*64;
    for (int t=tid; t<DM*64; t+=128){
      int dm = t>>6, kkl = t&63;
      lsW[dm*68 + kkl] = Wo[(size_t)dm*384 + colbase + kkl];
    }
    __syncthreads();
    const float* xb = xrow + c*64;
    for (int kk4=0; kk4<16; kk4++){
      float4 xv[8];
      #pragma unroll
      for (int i=0;i<8;i++) xv[i] = *(const float4*)(xb + (size_t)i*DI + kk4*4);
      #pragma unroll
      for (int q=0;q<3;q++){
        const float4 wv = *(const float4*)(&lsW[(cg+32*q)*68 + kk4*4]);
        #pragma unroll
        for (int i=0;i<8;i++){
          acc[i][q] = fmaf(xv[i].x, wv.x, acc[i][q]);
          acc[i][q] = fmaf(xv[i].y, wv.y, acc[i][q]);
          acc[i][q] = fmaf(xv[i].z, wv.z, acc[i][q]);
          acc[i][q] = fmaf(xv[i].w, wv.w, acc[i][q]);
        }
      }
    }
    __syncthreads();
  }
  #pragma unroll
  for (int i=0;i<8;i++){
    float* ob = out + (size_t)(row0 + r0 + i)*DM;
    #pragma unroll
    for (int q=0;q<3;q++) atomicAdd(&ob[cg + 32*q], acc[i][q]);
  }
}

// ---------------- launch ----------------
extern "C" void kernel_launch(void* const* d_in, const int* in_sizes, int n_in,
                              void* d_out, int out_size, void* d_ws, size_t ws_size,
                              hipStream_t stream) {
  const float* x_rgb      = (const float*)d_in[0];
  const float* x_e        = (const float*)d_in[1];
  const float* in_proj_w  = (const float*)d_in[2];
  const float* in_proj_xw = (const float*)d_in[3];
  const float* conv_w     = (const float*)d_in[4];
  const float* conv_b     = (const float*)d_in[5];
  const float* conv_xw    = (const float*)d_in[6];
  const float* conv_xb    = (const float*)d_in[7];
  const float* xpw        = (const float*)d_in[8];
  const float* dtw        = (const float*)d_in[9];
  const float* dtb        = (const float*)d_in[10];
  const float* A_logs     = (const float*)d_in[11];
  const float* Ds         = (const float*)d_in[12];
  const float* ln1_g      = (const float*)d_in[13];
  const float* ln1_b      = (const float*)d_in[14];
  const float* ln2_g      = (const float*)d_in[15];
  const float* ln2_b      = (const float*)d_in[16];
  const float* out_proj_w = (const float*)d_in[17];
  const float* fc1_w1     = (const float*)d_in[18];
  const float* fc1_w2     = (const float*)d_in[19];
  const float* fc2_w1     = (const float*)d_in[20];
  const float* fc2_w2     = (const float*)d_in[21];

  float* ws = (float*)d_ws;
  float* xr_t = ws;                        // 1,572,864
  float* xe_t = ws + 1572864;              // 1,572,864
  float* y0   = ws;                        // 3,145,728 (alias)
  float* seq  = ws + 3145728;              // 3,145,728
  float* yln  = seq;                       // alias
  float* y1   = ws + 6291456;              // 3,145,728
  float* P    = ws + 9437184;              //   458,752
  float* sr   = ws + 9895936;              //       768
  float* ex   = ws + 9896704;              //       768
  float* outp = (float*)d_out;

  k_zero  <<<dim3(3), 256, 0, stream>>>(sr, 768);
  k_inproj<<<dim3(HW/64, B_, 2), 256, 0, stream>>>(x_rgb, x_e, in_proj_w, in_proj_xw, xr_t, xe_t, sr);
  k_conv  <<<dim3(HW/256, DI, B_*2), 256, 0, stream>>>(xr_t, xe_t, conv_w, conv_b, conv_xw, conv_xb, seq);
  k_se    <<<dim3(B_, 2), DI, 0, stream>>>(sr, fc1_w1, fc1_w2, fc2_w1, fc2_w2, ex);
  k_proj  <<<dim3(LL/64, KD, B_), 256, 0, stream>>>(seq, xpw, P);
  k_scan  <<<dim3(B_*KD*DI), 256, 0, stream>>>(seq, P, dtw, dtb, A_logs, Ds, y0, y1);
  k_ln    <<<dim3(LL/64, B_), 256, 0, stream>>>(y0, y1, ln1_g, ln1_b, ln2_g, ln2_b, ex, yln);
  k_zero  <<<dim3((B_*HW*DM + 255)/256), 256, 0, stream>>>(outp, B_*HW*DM);
  k_out   <<<dim3(512), 128, 0, stream>>>(yln, out_proj_w, outp);
}